// Round 16
// baseline (308.368 us; speedup 1.0000x reference)
//
#include <hip/hip_runtime.h>

// ---------------- problem constants ----------------
constexpr int cN0 = 200000, cN1 = 50000, cN2 = 10000;
constexpr int cE0 = 800000, cE1 = 160000;
constexpr int GD  = 144;       // 32+16+16+16+64
constexpr int KP  = 160;       // padded K for MFMA (col 144 = bias-multiplier lane)
constexpr int HID = 256, OUTD = 128;
constexpr int KT  = 512;       // tail K = 2*HID

// ALL buckets are 64 dsts now (no quarter redundancy in agg0)
constexpr int WN   = 64, CAP = 1280;          // lambda~1023, +8 sigma
constexpr int NBA0 = (cN1 + WN - 1) / WN;     // 782 buckets/branch (L0)
constexpr int NBA1 = (cN2 + WN - 1) / WN;     // 157 buckets/branch (L1)
constexpr int NFILL = 2 * NBA0 + 2 * NBA1;    // 1878
constexpr size_t L1PBASE = (size_t)(2 * NBA0) * CAP;   // packed offset of L1 region

constexpr int GEMM_RB = (50048 + 255) / 256;  // 196 row-blocks
constexpr int TAIL_NB = cN2 / 16;             // 625
constexpr size_t UPLANE = (size_t)50048 * KP;
constexpr int BT_STRIDE = 144000;             // ushorts per branch hot-table

constexpr int CHUNK = 4096;                      // edges per bucketize block
constexpr int NCH0  = (cE0 + CHUNK - 1) / CHUNK; // 196
constexpr int NCH1  = (cE1 + CHUNK - 1) / CHUNK; // 40

typedef __attribute__((ext_vector_type(8))) short bf16x8;
typedef __attribute__((ext_vector_type(4))) float f32x4;
typedef unsigned long long u64;
constexpr u64 PXMASK = (1ull << 50) - 1;

__device__ __forceinline__ ushort f2bf(float f) {
  union { float f; unsigned u; } v; v.f = f;
  unsigned r = (v.u + 0x7FFFu + ((v.u >> 16) & 1u)) >> 16;
  return (ushort)r;
}
__device__ __forceinline__ float bf2f(ushort u) {
  union { unsigned u; float f; } v; v.u = ((unsigned)u) << 16;
  return v.f;
}

// ---------------- pack x rows into u64 (5 x 10-bit fields) ----------------
__global__ __launch_bounds__(256)
void pack_x(const int* __restrict__ x, u64* __restrict__ px) {
  int i = blockIdx.x * 256 + threadIdx.x;
  if (i < cN0) {
    const int* xp = x + (size_t)i * 5;
    u64 v = (u64)(xp[0] & 1023)
          | ((u64)(xp[1] & 1023) << 10)
          | ((u64)(xp[2] & 1023) << 20)
          | ((u64)(xp[3] & 1023) << 30)
          | ((u64)(xp[4] & 1023) << 40);
    px[i] = v;
  }
}

// ---------------- bf16 hot tables (rows 0..999 only live) ----------------
__global__ __launch_bounds__(144)
void build_btab(const float* __restrict__ s_t0, const float* __restrict__ s_t1,
                const float* __restrict__ s_t2, const float* __restrict__ s_t3,
                const float* __restrict__ s_t4,
                const float* __restrict__ c_t0, const float* __restrict__ c_t1,
                const float* __restrict__ c_t2, const float* __restrict__ c_t3,
                const float* __restrict__ c_t4,
                ushort* __restrict__ btab) {
  int br = blockIdx.x >> 10;
  int row = blockIdx.x & 1023;
  if (row >= 1000) return;
  int j = threadIdx.x;
  const float* t; int col, off, dim;
  if (j < 32)      { t = br ? c_t0 : s_t0; col = j;      off = 0;     dim = 32; }
  else if (j < 48) { t = br ? c_t1 : s_t1; col = j - 32; off = 32000; dim = 16; }
  else if (j < 64) { t = br ? c_t2 : s_t2; col = j - 48; off = 48000; dim = 16; }
  else if (j < 80) { t = br ? c_t3 : s_t3; col = j - 64; off = 64000; dim = 16; }
  else             { t = br ? c_t4 : s_t4; col = j - 80; off = 80000; dim = 64; }
  btab[(size_t)br * BT_STRIDE + off + row * dim + col] =
      f2bf(t[(size_t)row * dim + col]);
}

// ---------------- bucketize v7: 64-dst buckets, u64 records ----------------
// L0 record: bits 0..49 = px[src], bits 50..55 = local dst (0..63).
// L1 record: bits 0..17 = src,     bits 50..55 = local dst (0..63).
__global__ __launch_bounds__(512)
void bucketize_v7(const int* __restrict__ s0, const int* __restrict__ d0,
                  const int* __restrict__ s1, const int* __restrict__ d1,
                  const int* __restrict__ s2, const int* __restrict__ d2,
                  const int* __restrict__ s3, const int* __restrict__ d3,
                  const u64* __restrict__ px,
                  int* __restrict__ bfill, u64* __restrict__ packed) {
  __shared__ ushort rawD[CHUNK];                   // 8 KB
  __shared__ u64 sed[CHUNK];                       // 32 KB sorted records
  __shared__ int lcnt[NBA0], lstart[NBA0], gbase_s[NBA0], lfill[NBA0]; // 12.5 KB
  int bid = blockIdx.x, tid = threadIdx.x;
  const int *sp, *dp; int E, blk, NB, fbase, isL0;
  u64* pb;
  if (bid < NCH0) {
    sp = s0; dp = d0; E = cE0; blk = bid;             NB = NBA0;
    fbase = 0;               pb = packed; isL0 = 1;
  } else if (bid < 2 * NCH0) {
    sp = s1; dp = d1; E = cE0; blk = bid - NCH0;      NB = NBA0;
    fbase = NBA0;            pb = packed + (size_t)NBA0 * CAP; isL0 = 1;
  } else if (bid < 2 * NCH0 + NCH1) {
    sp = s2; dp = d2; E = cE1; blk = bid - 2 * NCH0;  NB = NBA1;
    fbase = 2 * NBA0;        pb = packed + L1PBASE; isL0 = 0;
  } else {
    sp = s3; dp = d3; E = cE1; blk = bid - 2 * NCH0 - NCH1; NB = NBA1;
    fbase = 2 * NBA0 + NBA1; pb = packed + L1PBASE + (size_t)NBA1 * CAP; isL0 = 0;
  }
  int base = blk * CHUNK;
  int n = min(CHUNK, E - base);

  for (int i = tid; i < NB; i += 512) { lcnt[i] = 0; lfill[i] = 0; }
  __syncthreads();
  // phase 1: batch 8 dst loads, then count 64-dst buckets
  {
    int dds[8];
    #pragma unroll
    for (int k = 0; k < 8; ++k) {
      int i = tid + k * 512;
      dds[k] = (i < n) ? dp[base + i] : -1;
    }
    #pragma unroll
    for (int k = 0; k < 8; ++k) {
      int i = tid + k * 512;
      if (i < n) {
        rawD[i] = (ushort)dds[k];
        atomicAdd(&lcnt[dds[k] >> 6], 1);
      }
    }
  }
  __syncthreads();
  // phase 2: single-wave exclusive scan (64 lanes x 13 bins = 832 >= NB)
  if (tid < 64) {
    int lane = tid;
    int i0 = lane * 13;
    int v[13], s = 0;
    #pragma unroll
    for (int j = 0; j < 13; ++j) {
      v[j] = (i0 + j < NB) ? lcnt[i0 + j] : 0;
      s += v[j];
    }
    int tot = s;
    #pragma unroll
    for (int off = 1; off < 64; off <<= 1) {
      int t = __shfl_up(s, off);
      if (lane >= off) s += t;
    }
    int excl = s - tot;
    #pragma unroll
    for (int j = 0; j < 13; ++j) {
      if (i0 + j < NB) lstart[i0 + j] = excl;
      excl += v[j];
    }
  }
  __syncthreads();
  // phase 3: batch src loads (+ px gathers for L0), scatter records to LDS
  {
    int srcs[8];
    #pragma unroll
    for (int k = 0; k < 8; ++k) {
      int i = tid + k * 512;
      srcs[k] = (i < n) ? sp[base + i] : 0;
    }
    u64 rec[8];
    if (isL0) {
      #pragma unroll
      for (int k = 0; k < 8; ++k) rec[k] = px[srcs[k]];
    } else {
      #pragma unroll
      for (int k = 0; k < 8; ++k) rec[k] = (u64)(unsigned)srcs[k];
    }
    #pragma unroll
    for (int k = 0; k < 8; ++k) {
      int i = tid + k * 512;
      if (i < n) {
        int dd = rawD[i];
        int b = dd >> 6;
        int p = atomicAdd(&lfill[b], 1);
        sed[lstart[b] + p] = rec[k] | ((u64)(unsigned)(dd & 63) << 50);
      }
    }
  }
  __syncthreads();
  // phase 4a: all per-bucket global atomics in parallel
  for (int b = tid; b < NB; b += 512) {
    int cnt = lcnt[b];
    gbase_s[b] = (cnt > 0) ? atomicAdd(&bfill[fbase + b], cnt) : 0;
  }
  __syncthreads();
  // phase 4b: copy-out (no atomics in loop; stores are fire-and-forget)
  int lane = tid & 63, wv = tid >> 6;
  for (int b = wv; b < NB; b += 8) {
    int cnt = lcnt[b];
    if (cnt == 0) continue;
    int gb0 = gbase_s[b];
    int st = lstart[b];
    for (int i = lane; i < cnt; i += 64) {
      int gp = gb0 + i;
      if (gp < CAP) pb[(size_t)b * CAP + gp] = sed[st + i];
    }
  }
}

// ---------------- fused layer-0: one block per 64-dst bucket ---------------
// grid: 2*NBA0 blocks of 256 threads (4 waves, 16 dsts each).
__global__ __launch_bounds__(256)
void agg0_fused(const u64* __restrict__ px, const ushort* __restrict__ btab,
                const int* __restrict__ bfill, const u64* __restrict__ packed,
                ushort* __restrict__ u) {
  __shared__ u64 lpx[CAP];                           // 10 KB (edge px records)
  __shared__ int lcnt[64], lstart[64], lfill[64];    // 768 B
  int tid = threadIdx.x, w = tid >> 6, lane = tid & 63;
  int gb = blockIdx.x;
  int br = gb / NBA0;
  int bk = gb - br * NBA0;
  int dst0 = bk * WN;
  int nd = min(WN, cN1 - dst0);

  const ushort* bt = btab + (size_t)br * BT_STRIDE;
  const ushort* gbase; int sh, gstride;
  bool has = (lane < 36);
  if (lane < 8)       { gbase = bt + lane * 4;                 sh = 0;  gstride = 32; }
  else if (lane < 12) { gbase = bt + 32000 + (lane - 8) * 4;   sh = 10; gstride = 16; }
  else if (lane < 16) { gbase = bt + 48000 + (lane - 12) * 4;  sh = 20; gstride = 16; }
  else if (lane < 20) { gbase = bt + 64000 + (lane - 16) * 4;  sh = 30; gstride = 16; }
  else if (lane < 36) { gbase = bt + 80000 + (lane - 20) * 4;  sh = 40; gstride = 64; }
  else                { gbase = bt;                            sh = 0;  gstride = 0;  }

  if (tid < 64) { lcnt[tid] = 0; lfill[tid] = 0; }
  __syncthreads();
  int ec = min(bfill[gb], CAP);
  const u64* pb = packed + (size_t)gb * CAP;
  // pass A: count per-dst (ALL records belong to this block)
  for (int i = tid; i < ec; i += 256)
    atomicAdd(&lcnt[(int)(pb[i] >> 50) & 63], 1);
  __syncthreads();
  // scan 64 bins (single wave)
  if (tid < 64) {
    int c = lcnt[tid]; int s = c;
    #pragma unroll
    for (int off = 1; off < 64; off <<= 1) {
      int t = __shfl_up(s, off);
      if (lane >= off) s += t;
    }
    lstart[tid] = s - c;
  }
  __syncthreads();
  // pass B: scatter px-records by dst
  for (int i = tid; i < ec; i += 256) {
    u64 v = pb[i];
    int l = (int)(v >> 50) & 63;
    int p = atomicAdd(&lfill[l], 1);
    lpx[lstart[l] + p] = v & PXMASK;
  }
  __syncthreads();

  for (int d = w; d < nd; d += 4) {
    int deg = lcnt[d], beg = lstart[d];
    float4 acc = make_float4(0.f, 0.f, 0.f, 0.f);
    int e = 0;
    for (; e + 8 <= deg; e += 8) {
      int rr[8];
      #pragma unroll
      for (int qq = 0; qq < 8; ++qq)
        rr[qq] = (int)((lpx[beg + e + qq] >> sh) & 1023ull);
      ushort4 g[8];
      #pragma unroll
      for (int qq = 0; qq < 8; ++qq)
        g[qq] = has ? *reinterpret_cast<const ushort4*>(gbase + (size_t)rr[qq] * gstride)
                    : make_ushort4(0, 0, 0, 0);
      #pragma unroll
      for (int qq = 0; qq < 8; ++qq) {
        acc.x += bf2f(g[qq].x); acc.y += bf2f(g[qq].y);
        acc.z += bf2f(g[qq].z); acc.w += bf2f(g[qq].w);
      }
    }
    for (; e < deg; ++e) {
      int r = (int)((lpx[beg + e] >> sh) & 1023ull);
      if (has) {
        const ushort4 g = *reinterpret_cast<const ushort4*>(gbase + (size_t)r * gstride);
        acc.x += bf2f(g.x); acc.y += bf2f(g.y); acc.z += bf2f(g.z); acc.w += bf2f(g.w);
      }
    }
    float invc = (deg > 0) ? 1.f / (float)deg : 0.f;
    int dg = dst0 + d;
    ushort* ur = u + (size_t)br * UPLANE + (size_t)dg * KP;
    u64 pvd = px[dg];
    if (has) {
      int rowd = (int)((pvd >> sh) & 1023ull);
      const ushort4 sv = *reinterpret_cast<const ushort4*>(gbase + (size_t)rowd * gstride);
      float4 r;
      r.x = bf2f(sv.x) + acc.x * invc;
      r.y = bf2f(sv.y) + acc.y * invc;
      r.z = bf2f(sv.z) + acc.z * invc;
      r.w = bf2f(sv.w) + acc.w * invc;
      ushort4 o;
      o.x = f2bf(r.x); o.y = f2bf(r.y); o.z = f2bf(r.z); o.w = f2bf(r.w);
      *reinterpret_cast<ushort4*>(ur + lane * 4) = o;
    } else if (lane == 36) {
      ushort4 o;
      o.x = f2bf(deg > 0 ? 2.f : 1.f);   // bias multiplier feature (col 144)
      o.y = 0; o.z = 0; o.w = 0;
      *reinterpret_cast<ushort4*>(ur + 144) = o;
    } else if (lane < 40) {
      *reinterpret_cast<ushort4*>(ur + lane * 4) = make_ushort4(0, 0, 0, 0);
    }
  }
}

// ---------------- W_in transpose+bf16+pad (+bias in row 144) ----------------
__global__ __launch_bounds__(KP)
void build_wt2(const float* __restrict__ Ws, const float* __restrict__ Wc,
               const float* __restrict__ bs, const float* __restrict__ bc,
               ushort* __restrict__ Wt) {
  int br = blockIdx.x >> 8, n = blockIdx.x & 255, k = threadIdx.x;
  const float* W = br ? Wc : Ws;
  const float* b = br ? bc : bs;
  float v = (k < GD) ? W[(size_t)k * HID + n] : ((k == GD) ? b[n] : 0.f);
  Wt[(size_t)br * HID * KP + n * KP + k] = f2bf(v);
}

// ---------------- layer-0 MFMA GEMM: h1 = relu(u@Wt^T), bf16 out -----------
__global__ __launch_bounds__(256)
void gemm_mfma2(const ushort* __restrict__ U, const ushort* __restrict__ Wt,
                ushort* __restrict__ h1) {
  __shared__ ushort Wth[128][KP + 8];
  int bid = blockIdx.x, tid = threadIdx.x;
  int rowblk = bid % GEMM_RB;
  int half = (bid / GEMM_RB) & 1;
  int br = bid / (2 * GEMM_RB);
  const ushort* Wsrc = Wt + ((size_t)br * HID + half * 128) * KP;
  for (int i = tid; i < 128 * (KP / 8); i += 256) {
    int r = i / (KP / 8), g = i - r * (KP / 8);
    *reinterpret_cast<bf16x8*>(&Wth[r][g * 8]) =
        *reinterpret_cast<const bf16x8*>(Wsrc + (size_t)r * KP + g * 8);
  }
  __syncthreads();
  int w = tid >> 6, lane = tid & 63, l15 = lane & 15, lhi = lane >> 4;
  int rowbase = rowblk * 256 + w * 64;
  const ushort* Ubr = U + (size_t)br * UPLANE;
  f32x4 acc[4][8];
  #pragma unroll
  for (int rt = 0; rt < 4; ++rt)
    #pragma unroll
    for (int ct = 0; ct < 8; ++ct) acc[rt][ct] = (f32x4){0.f, 0.f, 0.f, 0.f};
  #pragma unroll
  for (int ks = 0; ks < 5; ++ks) {
    bf16x8 bfr[8];
    #pragma unroll
    for (int ct = 0; ct < 8; ++ct)
      bfr[ct] = *reinterpret_cast<const bf16x8*>(&Wth[ct * 16 + l15][lhi * 8 + ks * 32]);
    #pragma unroll
    for (int rt = 0; rt < 4; ++rt) {
      int ar = rowbase + rt * 16 + l15;
      if (ar > 50047) ar = 50047;
      bf16x8 af = *reinterpret_cast<const bf16x8*>(Ubr + (size_t)ar * KP + lhi * 8 + ks * 32);
      #pragma unroll
      for (int ct = 0; ct < 8; ++ct)
        acc[rt][ct] = __builtin_amdgcn_mfma_f32_16x16x32_bf16(af, bfr[ct], acc[rt][ct], 0, 0, 0);
    }
  }
  ushort* h1p = h1 + (size_t)br * cN1 * HID + half * 128;
  #pragma unroll
  for (int rt = 0; rt < 4; ++rt) {
    #pragma unroll
    for (int r = 0; r < 4; ++r) {
      int row = rowbase + rt * 16 + lhi * 4 + r;
      if (row >= cN1) continue;
      #pragma unroll
      for (int ct = 0; ct < 8; ++ct)
        h1p[(size_t)row * HID + ct * 16 + l15] = f2bf(fmaxf(acc[rt][ct][r], 0.f));
    }
  }
}

// ---------------- fused layer-1: LDS sort + h1 mean-agg -> V bf16 ----------
__global__ __launch_bounds__(256)
void agg1_fused(const ushort* __restrict__ h1, const int* __restrict__ bfill,
                const u64* __restrict__ packed, ushort* __restrict__ V) {
  __shared__ u64 lvals[CAP];
  __shared__ int lsrc[CAP];
  __shared__ int lcnt[WN], lstart[WN], lfill[WN];
  int tid = threadIdx.x, w = tid >> 6, lane = tid & 63;
  int br = blockIdx.x / NBA1;
  int bk = blockIdx.x - br * NBA1;
  int fb = 2 * NBA0 + blockIdx.x;
  int dst0 = bk * WN;
  int nd = min(WN, cN2 - dst0);
  const ushort* h1p = h1 + (size_t)br * cN1 * HID;

  if (tid < WN) { lcnt[tid] = 0; lfill[tid] = 0; }
  __syncthreads();
  int ec = min(bfill[fb], CAP);
  const u64* pb = packed + L1PBASE + (size_t)blockIdx.x * CAP;
  for (int i = tid; i < ec; i += 256) {
    u64 v = pb[i];
    lvals[i] = v;
    atomicAdd(&lcnt[(int)((v >> 50) & 63ull)], 1);
  }
  __syncthreads();
  if (tid < 64) {
    int c = lcnt[tid]; int s = c;
    #pragma unroll
    for (int off = 1; off < 64; off <<= 1) {
      int t = __shfl_up(s, off);
      if (lane >= off) s += t;
    }
    lstart[tid] = s - c;
  }
  __syncthreads();
  for (int i = tid; i < ec; i += 256) {
    u64 v = lvals[i];
    int l = (int)((v >> 50) & 63ull);
    int p = atomicAdd(&lfill[l], 1);
    lsrc[lstart[l] + p] = (int)(v & 0x3FFFFull);
  }
  __syncthreads();

  for (int d = w; d < nd; d += 4) {
    int deg = lcnt[d], beg = lstart[d];
    float4 acc = make_float4(0.f, 0.f, 0.f, 0.f);
    int e = 0;
    for (; e + 4 <= deg; e += 4) {
      int sA = lsrc[beg + e], sB = lsrc[beg + e + 1];
      int sC = lsrc[beg + e + 2], sD = lsrc[beg + e + 3];
      ushort4 hA = *reinterpret_cast<const ushort4*>(h1p + (size_t)sA * HID + lane * 4);
      ushort4 hB = *reinterpret_cast<const ushort4*>(h1p + (size_t)sB * HID + lane * 4);
      ushort4 hC = *reinterpret_cast<const ushort4*>(h1p + (size_t)sC * HID + lane * 4);
      ushort4 hD = *reinterpret_cast<const ushort4*>(h1p + (size_t)sD * HID + lane * 4);
      acc.x += bf2f(hA.x) + bf2f(hB.x) + bf2f(hC.x) + bf2f(hD.x);
      acc.y += bf2f(hA.y) + bf2f(hB.y) + bf2f(hC.y) + bf2f(hD.y);
      acc.z += bf2f(hA.z) + bf2f(hB.z) + bf2f(hC.z) + bf2f(hD.z);
      acc.w += bf2f(hA.w) + bf2f(hB.w) + bf2f(hC.w) + bf2f(hD.w);
    }
    for (; e < deg; ++e) {
      int s = lsrc[beg + e];
      ushort4 hv = *reinterpret_cast<const ushort4*>(h1p + (size_t)s * HID + lane * 4);
      acc.x += bf2f(hv.x); acc.y += bf2f(hv.y); acc.z += bf2f(hv.z); acc.w += bf2f(hv.w);
    }
    float invc = (deg > 0) ? 1.f / (float)deg : 0.f;
    int dg = dst0 + d;
    ushort4 dv = *reinterpret_cast<const ushort4*>(h1p + (size_t)dg * HID + lane * 4);
    ushort4 o;
    o.x = f2bf(bf2f(dv.x) + acc.x * invc);
    o.y = f2bf(bf2f(dv.y) + acc.y * invc);
    o.z = f2bf(bf2f(dv.z) + acc.z * invc);
    o.w = f2bf(bf2f(dv.w) + acc.w * invc);
    *reinterpret_cast<ushort4*>(V + (size_t)dg * KT + br * HID + lane * 4) = o;
  }
}

// ---------------- integration weight folding ----------------
__global__ __launch_bounds__(128)
void build_small(const float* __restrict__ Ws2c, const float* __restrict__ Wc2s,
                 const float* __restrict__ a1p, const float* __restrict__ a2p,
                 const float* __restrict__ b2p, float* __restrict__ M) {
  int r = blockIdx.x, c = threadIdx.x;
  float A1 = a1p[0], A2 = a2p[0], B2 = b2p[0];
  float c0 = 1.f - A2 - B2;
  float c1 = A2 + B2 * (1.f - A1);
  float c2 = A1 * B2;
  float s1 = 0.f, s4 = 0.f;
  for (int k = 0; k < 128; ++k) {
    s1 += Ws2c[r * 128 + k] * Wc2s[k * 128 + c];
    s4 += Wc2s[r * 128 + k] * Ws2c[k * 128 + c];
  }
  float eye = (r == c) ? c0 : 0.f;
  M[0 * 16384 + r * 128 + c] = c2 * s1 + eye;
  M[1 * 16384 + r * 128 + c] = c1 * Wc2s[r * 128 + c];
  M[2 * 16384 + r * 128 + c] = c1 * Ws2c[r * 128 + c];
  M[3 * 16384 + r * 128 + c] = c2 * s4 + eye;
}

__global__ __launch_bounds__(256)
void build_G(const float* __restrict__ Wout_s, const float* __restrict__ Wout_c,
             const float* __restrict__ M, ushort* __restrict__ Gt) {
  __shared__ float wr[128];
  int k = blockIdx.x, j = threadIdx.x;
  const float* wrow = (k < 256) ? &Wout_s[(size_t)k * 128] : &Wout_c[(size_t)(k - 256) * 128];
  if (j < 128) wr[j] = wrow[j];
  __syncthreads();
  const float* Mm = (j < 128) ? (k < 256 ? M : M + 16384)
                              : (k < 256 ? M + 2 * 16384 : M + 3 * 16384);
  int jj = j & 127;
  float s = 0.f;
  for (int t = 0; t < 128; ++t) s += wr[t] * Mm[t * 128 + jj];
  Gt[(size_t)j * KT + k] = f2bf(s);
}

__global__ __launch_bounds__(256)
void build_gvec(const float* __restrict__ b_s, const float* __restrict__ b_c,
                const float* __restrict__ M, float* __restrict__ gvec) {
  int j = threadIdx.x, jj = j & 127;
  const float* Ma = (j < 128) ? M : M + 2 * 16384;
  const float* Mb = (j < 128) ? M + 16384 : M + 3 * 16384;
  float s = 0.f;
  for (int t = 0; t < 128; ++t)
    s += b_s[t] * Ma[t * 128 + jj] + b_c[t] * Mb[t * 128 + jj];
  gvec[j] = s;
}

// ---------------- tail MFMA GEMM: out = V @ Gt^T + gvec ----------------
__global__ __launch_bounds__(64)
void tail_gemm(const ushort* __restrict__ V, const ushort* __restrict__ Gt,
               const float* __restrict__ gvec, float* __restrict__ out) {
  int lane = threadIdx.x;
  int l15 = lane & 15, lhi = lane >> 4;
  int rowW = blockIdx.x * 16;
  f32x4 acc[16];
  #pragma unroll
  for (int t = 0; t < 16; ++t) acc[t] = (f32x4){0.f, 0.f, 0.f, 0.f};
  const ushort* vp = V + (size_t)(rowW + l15) * KT + lhi * 8;
  const ushort* gp = Gt + (size_t)l15 * KT + lhi * 8;
  #pragma unroll
  for (int ks = 0; ks < 16; ++ks) {
    bf16x8 a = *reinterpret_cast<const bf16x8*>(vp + ks * 32);
    #pragma unroll
    for (int t = 0; t < 16; ++t) {
      bf16x8 b = *reinterpret_cast<const bf16x8*>(gp + (size_t)t * 16 * KT + ks * 32);
      acc[t] = __builtin_amdgcn_mfma_f32_16x16x32_bf16(a, b, acc[t], 0, 0, 0);
    }
  }
  int r0 = rowW + lhi * 4;
  #pragma unroll
  for (int t = 0; t < 16; ++t) {
    int col = t * 16 + l15;
    float gv = gvec[col];
    float* dst = (col < 128) ? out + (size_t)r0 * OUTD + col
                             : out + (size_t)cN2 * OUTD + (size_t)r0 * OUTD + (col - 128);
    #pragma unroll
    for (int r = 0; r < 4; ++r)
      dst[(size_t)r * OUTD] = acc[t][r] + gv;
  }
}

// ---------------- launch ----------------
extern "C" void kernel_launch(void* const* d_in, const int* in_sizes, int n_in,
                              void* d_out, int out_size, void* d_ws, size_t ws_size,
                              hipStream_t stream) {
  const int* x = (const int*)d_in[0];
  struct Branch {
    const int *e0s, *e0d, *e1s, *e1d;
    const float *t0, *t1, *t2, *t3, *t4, *Win, *bin, *Wout, *bout;
  };
  auto mk = [&](int b) {
    Branch B;
    B.e0s = (const int*)d_in[b + 0];
    B.e0d = (const int*)d_in[b + 1];
    B.e1s = (const int*)d_in[b + 2];
    B.e1d = (const int*)d_in[b + 3];
    B.t0  = (const float*)d_in[b + 4];
    B.t1  = (const float*)d_in[b + 5];
    B.t2  = (const float*)d_in[b + 6];
    B.t3  = (const float*)d_in[b + 7];
    B.t4  = (const float*)d_in[b + 8];
    B.Win = (const float*)d_in[b + 9];
    B.bin = (const float*)d_in[b + 10];
    B.Wout= (const float*)d_in[b + 11];
    B.bout= (const float*)d_in[b + 12];
    return B;
  };
  Branch SB = mk(1), CB = mk(14);
  const float* Ws2c = (const float*)d_in[27];
  const float* Wc2s = (const float*)d_in[28];
  const float* a1p  = (const float*)d_in[29];
  const float* a2p  = (const float*)d_in[30];
  const float* b2p  = (const float*)d_in[31];

  // workspace layout (px/btab alias V region — V written only in agg1, after
  // px/btab's last reads in agg0)
  char* ws = (char*)d_ws;
  ushort* u    = (ushort*)(ws + 0);            // 32,030,720
  ushort* h1   = (ushort*)(ws + 32030720);     // 51,200,000
  ushort* V    = (ushort*)(ws + 83230720);     // 10,240,000
  u64*   px    = (u64*)   (ws + 83230720);     // 1,600,000 (alias V)
  ushort* btab = (ushort*)(ws + 84830720);     // 576,000 (alias V)
  float*  M    = (float*) (ws + 93470720);     // 262,144
  ushort* Gt   = (ushort*)(ws + 93732864);     // 262,144
  float*  gvec = (float*) (ws + 93995008);     // 1,024
  ushort* Wt   = (ushort*)(ws + 93996032);     // 163,840
  int*   bfill = (int*)   (ws + 94159872);     // 1878*4 (pad to 7,680)
  u64*   packed= (u64*)   (ws + 94167552);     // 1878*1280*8 = 19,230,720 (end ~113.4MB)

  hipMemsetAsync(bfill, 0, NFILL * sizeof(int), stream);

  // weight folding + x packing + hot tables (independent of graph work)
  pack_x<<<(cN0 + 255) / 256, 256, 0, stream>>>(x, px);
  build_btab<<<2048, 144, 0, stream>>>(
      SB.t0, SB.t1, SB.t2, SB.t3, SB.t4,
      CB.t0, CB.t1, CB.t2, CB.t3, CB.t4, btab);
  build_wt2<<<512, KP, 0, stream>>>(SB.Win, CB.Win, SB.bin, CB.bin, Wt);
  build_small<<<128, 128, 0, stream>>>(Ws2c, Wc2s, a1p, a2p, b2p, M);
  build_G<<<512, 256, 0, stream>>>(SB.Wout, CB.Wout, M, Gt);
  build_gvec<<<1, 256, 0, stream>>>(SB.bout, CB.bout, M, gvec);

  // edge bucketing (64-dst buckets; records carry px for L0)
  bucketize_v7<<<2 * NCH0 + 2 * NCH1, 512, 0, stream>>>(
      SB.e0s, SB.e0d, CB.e0s, CB.e0d, SB.e1s, SB.e1d, CB.e1s, CB.e1d,
      px, bfill, packed);

  // compute pipeline
  agg0_fused<<<2 * NBA0, 256, 0, stream>>>(px, btab, bfill, packed, u);
  gemm_mfma2<<<4 * GEMM_RB, 256, 0, stream>>>(u, Wt, h1);
  agg1_fused<<<2 * NBA1, 256, 0, stream>>>(h1, bfill, packed, V);
  tail_gemm<<<TAIL_NB, 64, 0, stream>>>(V, Gt, gvec, (float*)d_out);
}

// Round 17
// 281.246 us; speedup vs baseline: 1.0964x; 1.0964x over previous
//
#include <hip/hip_runtime.h>

// ---------------- problem constants ----------------
constexpr int cN0 = 200000, cN1 = 50000, cN2 = 10000;
constexpr int cE0 = 800000, cE1 = 160000;
constexpr int GD  = 144;
constexpr int KP  = 160;       // padded K for MFMA (col 144 = bias-multiplier lane)
constexpr int HID = 256, OUTD = 128;
constexpr int KT  = 512;

constexpr int WN   = 64, CAP = 1280;
constexpr int NBA0 = (cN1 + WN - 1) / WN;     // 782
constexpr int NBA1 = (cN2 + WN - 1) / WN;     // 157
constexpr int NFILL = 2 * NBA0 + 2 * NBA1;    // 1878
constexpr size_t L1PBASE = (size_t)(2 * NBA0) * CAP;

constexpr int GEMM_RB = (50048 + 255) / 256;  // 196
constexpr int TAIL_NB = cN2 / 16;             // 625
constexpr size_t UPLANE = (size_t)50048 * KP;
constexpr int BT_STRIDE = 144000;

constexpr int CHUNK = 4096;
constexpr int NCH0  = (cE0 + CHUNK - 1) / CHUNK; // 196
constexpr int NCH1  = (cE1 + CHUNK - 1) / CHUNK; // 40

typedef __attribute__((ext_vector_type(8))) short bf16x8;
typedef __attribute__((ext_vector_type(4))) float f32x4;
typedef unsigned long long u64;
constexpr u64 PXMASK = (1ull << 50) - 1;

__device__ __forceinline__ ushort f2bf(float f) {
  union { float f; unsigned u; } v; v.f = f;
  unsigned r = (v.u + 0x7FFFu + ((v.u >> 16) & 1u)) >> 16;
  return (ushort)r;
}
__device__ __forceinline__ float bf2f(ushort u) {
  union { unsigned u; float f; } v; v.u = ((unsigned)u) << 16;
  return v.f;
}
__device__ __forceinline__ float bflo(unsigned v) {
  union { unsigned u; float f; } x; x.u = v << 16; return x.f;
}
__device__ __forceinline__ float bfhi(unsigned v) {
  union { unsigned u; float f; } x; x.u = v & 0xFFFF0000u; return x.f;
}

// ---------------- pack x rows into u64 (5 x 10-bit fields) ----------------
__global__ __launch_bounds__(256)
void pack_x(const int* __restrict__ x, u64* __restrict__ px) {
  int i = blockIdx.x * 256 + threadIdx.x;
  if (i < cN0) {
    const int* xp = x + (size_t)i * 5;
    u64 v = (u64)(xp[0] & 1023)
          | ((u64)(xp[1] & 1023) << 10)
          | ((u64)(xp[2] & 1023) << 20)
          | ((u64)(xp[3] & 1023) << 30)
          | ((u64)(xp[4] & 1023) << 40);
    px[i] = v;
  }
}

// ---------------- bf16 hot tables (rows 0..999 only live) ----------------
__global__ __launch_bounds__(144)
void build_btab(const float* __restrict__ s_t0, const float* __restrict__ s_t1,
                const float* __restrict__ s_t2, const float* __restrict__ s_t3,
                const float* __restrict__ s_t4,
                const float* __restrict__ c_t0, const float* __restrict__ c_t1,
                const float* __restrict__ c_t2, const float* __restrict__ c_t3,
                const float* __restrict__ c_t4,
                ushort* __restrict__ btab) {
  int br = blockIdx.x >> 10;
  int row = blockIdx.x & 1023;
  if (row >= 1000) return;
  int j = threadIdx.x;
  const float* t; int col, off, dim;
  if (j < 32)      { t = br ? c_t0 : s_t0; col = j;      off = 0;     dim = 32; }
  else if (j < 48) { t = br ? c_t1 : s_t1; col = j - 32; off = 32000; dim = 16; }
  else if (j < 64) { t = br ? c_t2 : s_t2; col = j - 48; off = 48000; dim = 16; }
  else if (j < 80) { t = br ? c_t3 : s_t3; col = j - 64; off = 64000; dim = 16; }
  else             { t = br ? c_t4 : s_t4; col = j - 80; off = 80000; dim = 64; }
  btab[(size_t)br * BT_STRIDE + off + row * dim + col] =
      f2bf(t[(size_t)row * dim + col]);
}

// ---------------- bucketize v7 (unchanged from R15) ----------------
__global__ __launch_bounds__(512)
void bucketize_v7(const int* __restrict__ s0, const int* __restrict__ d0,
                  const int* __restrict__ s1, const int* __restrict__ d1,
                  const int* __restrict__ s2, const int* __restrict__ d2,
                  const int* __restrict__ s3, const int* __restrict__ d3,
                  const u64* __restrict__ px,
                  int* __restrict__ bfill, u64* __restrict__ packed) {
  __shared__ ushort rawD[CHUNK];
  __shared__ u64 sed[CHUNK];
  __shared__ int lcnt[NBA0], lstart[NBA0], gbase_s[NBA0], lfill[NBA0];
  int bid = blockIdx.x, tid = threadIdx.x;
  const int *sp, *dp; int E, blk, NB, fbase, isL0;
  u64* pb;
  if (bid < NCH0) {
    sp = s0; dp = d0; E = cE0; blk = bid;             NB = NBA0;
    fbase = 0;               pb = packed; isL0 = 1;
  } else if (bid < 2 * NCH0) {
    sp = s1; dp = d1; E = cE0; blk = bid - NCH0;      NB = NBA0;
    fbase = NBA0;            pb = packed + (size_t)NBA0 * CAP; isL0 = 1;
  } else if (bid < 2 * NCH0 + NCH1) {
    sp = s2; dp = d2; E = cE1; blk = bid - 2 * NCH0;  NB = NBA1;
    fbase = 2 * NBA0;        pb = packed + L1PBASE; isL0 = 0;
  } else {
    sp = s3; dp = d3; E = cE1; blk = bid - 2 * NCH0 - NCH1; NB = NBA1;
    fbase = 2 * NBA0 + NBA1; pb = packed + L1PBASE + (size_t)NBA1 * CAP; isL0 = 0;
  }
  int base = blk * CHUNK;
  int n = min(CHUNK, E - base);

  for (int i = tid; i < NB; i += 512) { lcnt[i] = 0; lfill[i] = 0; }
  __syncthreads();
  {
    int dds[8];
    #pragma unroll
    for (int k = 0; k < 8; ++k) {
      int i = tid + k * 512;
      dds[k] = (i < n) ? dp[base + i] : -1;
    }
    #pragma unroll
    for (int k = 0; k < 8; ++k) {
      int i = tid + k * 512;
      if (i < n) {
        rawD[i] = (ushort)dds[k];
        atomicAdd(&lcnt[dds[k] >> 6], 1);
      }
    }
  }
  __syncthreads();
  if (tid < 64) {
    int lane = tid;
    int i0 = lane * 13;
    int v[13], s = 0;
    #pragma unroll
    for (int j = 0; j < 13; ++j) {
      v[j] = (i0 + j < NB) ? lcnt[i0 + j] : 0;
      s += v[j];
    }
    int tot = s;
    #pragma unroll
    for (int off = 1; off < 64; off <<= 1) {
      int t = __shfl_up(s, off);
      if (lane >= off) s += t;
    }
    int excl = s - tot;
    #pragma unroll
    for (int j = 0; j < 13; ++j) {
      if (i0 + j < NB) lstart[i0 + j] = excl;
      excl += v[j];
    }
  }
  __syncthreads();
  {
    int srcs[8];
    #pragma unroll
    for (int k = 0; k < 8; ++k) {
      int i = tid + k * 512;
      srcs[k] = (i < n) ? sp[base + i] : 0;
    }
    u64 rec[8];
    if (isL0) {
      #pragma unroll
      for (int k = 0; k < 8; ++k) rec[k] = px[srcs[k]];
    } else {
      #pragma unroll
      for (int k = 0; k < 8; ++k) rec[k] = (u64)(unsigned)srcs[k];
    }
    #pragma unroll
    for (int k = 0; k < 8; ++k) {
      int i = tid + k * 512;
      if (i < n) {
        int dd = rawD[i];
        int b = dd >> 6;
        int p = atomicAdd(&lfill[b], 1);
        sed[lstart[b] + p] = rec[k] | ((u64)(unsigned)(dd & 63) << 50);
      }
    }
  }
  __syncthreads();
  for (int b = tid; b < NB; b += 512) {
    int cnt = lcnt[b];
    gbase_s[b] = (cnt > 0) ? atomicAdd(&bfill[fbase + b], cnt) : 0;
  }
  __syncthreads();
  int lane = tid & 63, wv = tid >> 6;
  for (int b = wv; b < NB; b += 8) {
    int cnt = lcnt[b];
    if (cnt == 0) continue;
    int gb0 = gbase_s[b];
    int st = lstart[b];
    for (int i = lane; i < cnt; i += 64) {
      int gp = gb0 + i;
      if (gp < CAP) pb[(size_t)b * CAP + gp] = sed[st + i];
    }
  }
}

// ---------------- fused layer-0: 18-lane x ushort8, 3 edges/pass -----------
// grid: 2*NBA0 blocks of 256 threads (4 waves, 16 dsts each).
__global__ __launch_bounds__(256)
void agg0_fused(const u64* __restrict__ px, const ushort* __restrict__ btab,
                const int* __restrict__ bfill, const u64* __restrict__ packed,
                ushort* __restrict__ u) {
  __shared__ u64 lpx[CAP];
  __shared__ int lcnt[64], lstart[64], lfill[64];
  int tid = threadIdx.x, w = tid >> 6, lane = tid & 63;
  int gb = blockIdx.x;
  int br = gb / NBA0;
  int bk = gb - br * NBA0;
  int dst0 = bk * WN;
  int nd = min(WN, cN1 - dst0);

  const ushort* bt = btab + (size_t)br * BT_STRIDE;
  int sub = lane / 18;            // 0,1,2 active; 3 = idle (lanes 54-63)
  int g   = lane - sub * 18;      // 0..17 (dims 8g..8g+7)
  const ushort* gbase; int sh, gstride;
  if (g < 4)       { gbase = bt + g * 8;              sh = 0;  gstride = 32; }
  else if (g < 6)  { gbase = bt + 32000 + (g - 4) * 8; sh = 10; gstride = 16; }
  else if (g < 8)  { gbase = bt + 48000 + (g - 6) * 8; sh = 20; gstride = 16; }
  else if (g < 10) { gbase = bt + 64000 + (g - 8) * 8; sh = 30; gstride = 16; }
  else             { gbase = bt + 80000 + (g - 10) * 8; sh = 40; gstride = 64; }

  if (tid < 64) { lcnt[tid] = 0; lfill[tid] = 0; }
  __syncthreads();
  int ec = min(bfill[gb], CAP);
  const u64* pb = packed + (size_t)gb * CAP;
  // pass A: count per-dst
  for (int i = tid; i < ec; i += 256)
    atomicAdd(&lcnt[(int)(pb[i] >> 50) & 63], 1);
  __syncthreads();
  // scan 64 bins (single wave)
  if (tid < 64) {
    int c = lcnt[tid]; int s = c;
    #pragma unroll
    for (int off = 1; off < 64; off <<= 1) {
      int t = __shfl_up(s, off);
      if (lane >= off) s += t;
    }
    lstart[tid] = s - c;
  }
  __syncthreads();
  // pass B: scatter px-records by dst
  for (int i = tid; i < ec; i += 256) {
    u64 v = pb[i];
    int l = (int)(v >> 50) & 63;
    int p = atomicAdd(&lfill[l], 1);
    lpx[lstart[l] + p] = v & PXMASK;
  }
  __syncthreads();

  for (int d = w; d < nd; d += 4) {
    int deg = lcnt[d], beg = lstart[d];
    float acc[8];
    #pragma unroll
    for (int j = 0; j < 8; ++j) acc[j] = 0.f;
    int e0 = (sub < 3) ? sub : deg;
    for (int e = e0; e < deg; e += 3) {
      u64 rec = lpx[beg + e];
      int r = (int)((rec >> sh) & 1023ull);
      uint4 gv = *reinterpret_cast<const uint4*>(gbase + (size_t)r * gstride);
      acc[0] += bflo(gv.x); acc[1] += bfhi(gv.x);
      acc[2] += bflo(gv.y); acc[3] += bfhi(gv.y);
      acc[4] += bflo(gv.z); acc[5] += bfhi(gv.z);
      acc[6] += bflo(gv.w); acc[7] += bfhi(gv.w);
    }
    // cross-sub reduce: lanes g, 18+g, 36+g hold partials for dims 8g..8g+7
    #pragma unroll
    for (int j = 0; j < 8; ++j) {
      float a1 = __shfl(acc[j], lane + 18);
      float a2 = __shfl(acc[j], lane + 36);
      acc[j] += a1 + a2;
    }
    float invc = (deg > 0) ? 1.f / (float)deg : 0.f;
    int dg = dst0 + d;
    ushort* ur = u + (size_t)br * UPLANE + (size_t)dg * KP;
    if (sub == 0) {
      u64 pvd = px[dg];
      int rowd = (int)((pvd >> sh) & 1023ull);
      uint4 sv = *reinterpret_cast<const uint4*>(gbase + (size_t)rowd * gstride);
      float s[8];
      s[0] = bflo(sv.x); s[1] = bfhi(sv.x);
      s[2] = bflo(sv.y); s[3] = bfhi(sv.y);
      s[4] = bflo(sv.z); s[5] = bfhi(sv.z);
      s[6] = bflo(sv.w); s[7] = bfhi(sv.w);
      bf16x8 o;
      #pragma unroll
      for (int j = 0; j < 8; ++j) o[j] = (short)f2bf(s[j] + acc[j] * invc);
      *reinterpret_cast<bf16x8*>(ur + g * 8) = o;
    } else if (lane == 18) {
      bf16x8 o = (bf16x8){0, 0, 0, 0, 0, 0, 0, 0};
      o[0] = (short)f2bf(deg > 0 ? 2.f : 1.f);   // bias-mult feature (col 144)
      *reinterpret_cast<bf16x8*>(ur + 144) = o;
    } else if (lane == 19) {
      *reinterpret_cast<bf16x8*>(ur + 152) = (bf16x8){0, 0, 0, 0, 0, 0, 0, 0};
    }
  }
}

// ---------------- W_in transpose+bf16+pad (+bias in row 144) ----------------
__global__ __launch_bounds__(KP)
void build_wt2(const float* __restrict__ Ws, const float* __restrict__ Wc,
               const float* __restrict__ bs, const float* __restrict__ bc,
               ushort* __restrict__ Wt) {
  int br = blockIdx.x >> 8, n = blockIdx.x & 255, k = threadIdx.x;
  const float* W = br ? Wc : Ws;
  const float* b = br ? bc : bs;
  float v = (k < GD) ? W[(size_t)k * HID + n] : ((k == GD) ? b[n] : 0.f);
  Wt[(size_t)br * HID * KP + n * KP + k] = f2bf(v);
}

// ---------------- layer-0 MFMA GEMM: h1 = relu(u@Wt^T), bf16 out -----------
__global__ __launch_bounds__(256)
void gemm_mfma2(const ushort* __restrict__ U, const ushort* __restrict__ Wt,
                ushort* __restrict__ h1) {
  __shared__ ushort Wth[128][KP + 8];
  int bid = blockIdx.x, tid = threadIdx.x;
  int rowblk = bid % GEMM_RB;
  int half = (bid / GEMM_RB) & 1;
  int br = bid / (2 * GEMM_RB);
  const ushort* Wsrc = Wt + ((size_t)br * HID + half * 128) * KP;
  for (int i = tid; i < 128 * (KP / 8); i += 256) {
    int r = i / (KP / 8), g = i - r * (KP / 8);
    *reinterpret_cast<bf16x8*>(&Wth[r][g * 8]) =
        *reinterpret_cast<const bf16x8*>(Wsrc + (size_t)r * KP + g * 8);
  }
  __syncthreads();
  int w = tid >> 6, lane = tid & 63, l15 = lane & 15, lhi = lane >> 4;
  int rowbase = rowblk * 256 + w * 64;
  const ushort* Ubr = U + (size_t)br * UPLANE;
  f32x4 acc[4][8];
  #pragma unroll
  for (int rt = 0; rt < 4; ++rt)
    #pragma unroll
    for (int ct = 0; ct < 8; ++ct) acc[rt][ct] = (f32x4){0.f, 0.f, 0.f, 0.f};
  #pragma unroll
  for (int ks = 0; ks < 5; ++ks) {
    bf16x8 bfr[8];
    #pragma unroll
    for (int ct = 0; ct < 8; ++ct)
      bfr[ct] = *reinterpret_cast<const bf16x8*>(&Wth[ct * 16 + l15][lhi * 8 + ks * 32]);
    #pragma unroll
    for (int rt = 0; rt < 4; ++rt) {
      int ar = rowbase + rt * 16 + l15;
      if (ar > 50047) ar = 50047;
      bf16x8 af = *reinterpret_cast<const bf16x8*>(Ubr + (size_t)ar * KP + lhi * 8 + ks * 32);
      #pragma unroll
      for (int ct = 0; ct < 8; ++ct)
        acc[rt][ct] = __builtin_amdgcn_mfma_f32_16x16x32_bf16(af, bfr[ct], acc[rt][ct], 0, 0, 0);
    }
  }
  ushort* h1p = h1 + (size_t)br * cN1 * HID + half * 128;
  #pragma unroll
  for (int rt = 0; rt < 4; ++rt) {
    #pragma unroll
    for (int r = 0; r < 4; ++r) {
      int row = rowbase + rt * 16 + lhi * 4 + r;
      if (row >= cN1) continue;
      #pragma unroll
      for (int ct = 0; ct < 8; ++ct)
        h1p[(size_t)row * HID + ct * 16 + l15] = f2bf(fmaxf(acc[rt][ct][r], 0.f));
    }
  }
}

// ---------------- fused layer-1: LDS sort + h1 mean-agg -> V bf16 ----------
__global__ __launch_bounds__(256)
void agg1_fused(const ushort* __restrict__ h1, const int* __restrict__ bfill,
                const u64* __restrict__ packed, ushort* __restrict__ V) {
  __shared__ u64 lvals[CAP];
  __shared__ int lsrc[CAP];
  __shared__ int lcnt[WN], lstart[WN], lfill[WN];
  int tid = threadIdx.x, w = tid >> 6, lane = tid & 63;
  int br = blockIdx.x / NBA1;
  int bk = blockIdx.x - br * NBA1;
  int fb = 2 * NBA0 + blockIdx.x;
  int dst0 = bk * WN;
  int nd = min(WN, cN2 - dst0);
  const ushort* h1p = h1 + (size_t)br * cN1 * HID;

  if (tid < WN) { lcnt[tid] = 0; lfill[tid] = 0; }
  __syncthreads();
  int ec = min(bfill[fb], CAP);
  const u64* pb = packed + L1PBASE + (size_t)blockIdx.x * CAP;
  for (int i = tid; i < ec; i += 256) {
    u64 v = pb[i];
    lvals[i] = v;
    atomicAdd(&lcnt[(int)((v >> 50) & 63ull)], 1);
  }
  __syncthreads();
  if (tid < 64) {
    int c = lcnt[tid]; int s = c;
    #pragma unroll
    for (int off = 1; off < 64; off <<= 1) {
      int t = __shfl_up(s, off);
      if (lane >= off) s += t;
    }
    lstart[tid] = s - c;
  }
  __syncthreads();
  for (int i = tid; i < ec; i += 256) {
    u64 v = lvals[i];
    int l = (int)((v >> 50) & 63ull);
    int p = atomicAdd(&lfill[l], 1);
    lsrc[lstart[l] + p] = (int)(v & 0x3FFFFull);
  }
  __syncthreads();

  for (int d = w; d < nd; d += 4) {
    int deg = lcnt[d], beg = lstart[d];
    float4 acc = make_float4(0.f, 0.f, 0.f, 0.f);
    int e = 0;
    for (; e + 4 <= deg; e += 4) {
      int sA = lsrc[beg + e], sB = lsrc[beg + e + 1];
      int sC = lsrc[beg + e + 2], sD = lsrc[beg + e + 3];
      ushort4 hA = *reinterpret_cast<const ushort4*>(h1p + (size_t)sA * HID + lane * 4);
      ushort4 hB = *reinterpret_cast<const ushort4*>(h1p + (size_t)sB * HID + lane * 4);
      ushort4 hC = *reinterpret_cast<const ushort4*>(h1p + (size_t)sC * HID + lane * 4);
      ushort4 hD = *reinterpret_cast<const ushort4*>(h1p + (size_t)sD * HID + lane * 4);
      acc.x += bf2f(hA.x) + bf2f(hB.x) + bf2f(hC.x) + bf2f(hD.x);
      acc.y += bf2f(hA.y) + bf2f(hB.y) + bf2f(hC.y) + bf2f(hD.y);
      acc.z += bf2f(hA.z) + bf2f(hB.z) + bf2f(hC.z) + bf2f(hD.z);
      acc.w += bf2f(hA.w) + bf2f(hB.w) + bf2f(hC.w) + bf2f(hD.w);
    }
    for (; e < deg; ++e) {
      int s = lsrc[beg + e];
      ushort4 hv = *reinterpret_cast<const ushort4*>(h1p + (size_t)s * HID + lane * 4);
      acc.x += bf2f(hv.x); acc.y += bf2f(hv.y); acc.z += bf2f(hv.z); acc.w += bf2f(hv.w);
    }
    float invc = (deg > 0) ? 1.f / (float)deg : 0.f;
    int dg = dst0 + d;
    ushort4 dv = *reinterpret_cast<const ushort4*>(h1p + (size_t)dg * HID + lane * 4);
    ushort4 o;
    o.x = f2bf(bf2f(dv.x) + acc.x * invc);
    o.y = f2bf(bf2f(dv.y) + acc.y * invc);
    o.z = f2bf(bf2f(dv.z) + acc.z * invc);
    o.w = f2bf(bf2f(dv.w) + acc.w * invc);
    *reinterpret_cast<ushort4*>(V + (size_t)dg * KT + br * HID + lane * 4) = o;
  }
}

// ---------------- integration weight folding ----------------
__global__ __launch_bounds__(128)
void build_small(const float* __restrict__ Ws2c, const float* __restrict__ Wc2s,
                 const float* __restrict__ a1p, const float* __restrict__ a2p,
                 const float* __restrict__ b2p, float* __restrict__ M) {
  int r = blockIdx.x, c = threadIdx.x;
  float A1 = a1p[0], A2 = a2p[0], B2 = b2p[0];
  float c0 = 1.f - A2 - B2;
  float c1 = A2 + B2 * (1.f - A1);
  float c2 = A1 * B2;
  float s1 = 0.f, s4 = 0.f;
  for (int k = 0; k < 128; ++k) {
    s1 += Ws2c[r * 128 + k] * Wc2s[k * 128 + c];
    s4 += Wc2s[r * 128 + k] * Ws2c[k * 128 + c];
  }
  float eye = (r == c) ? c0 : 0.f;
  M[0 * 16384 + r * 128 + c] = c2 * s1 + eye;
  M[1 * 16384 + r * 128 + c] = c1 * Wc2s[r * 128 + c];
  M[2 * 16384 + r * 128 + c] = c1 * Ws2c[r * 128 + c];
  M[3 * 16384 + r * 128 + c] = c2 * s4 + eye;
}

__global__ __launch_bounds__(256)
void build_G(const float* __restrict__ Wout_s, const float* __restrict__ Wout_c,
             const float* __restrict__ M, ushort* __restrict__ Gt) {
  __shared__ float wr[128];
  int k = blockIdx.x, j = threadIdx.x;
  const float* wrow = (k < 256) ? &Wout_s[(size_t)k * 128] : &Wout_c[(size_t)(k - 256) * 128];
  if (j < 128) wr[j] = wrow[j];
  __syncthreads();
  const float* Mm = (j < 128) ? (k < 256 ? M : M + 16384)
                              : (k < 256 ? M + 2 * 16384 : M + 3 * 16384);
  int jj = j & 127;
  float s = 0.f;
  for (int t = 0; t < 128; ++t) s += wr[t] * Mm[t * 128 + jj];
  Gt[(size_t)j * KT + k] = f2bf(s);
}

__global__ __launch_bounds__(256)
void build_gvec(const float* __restrict__ b_s, const float* __restrict__ b_c,
                const float* __restrict__ M, float* __restrict__ gvec) {
  int j = threadIdx.x, jj = j & 127;
  const float* Ma = (j < 128) ? M : M + 2 * 16384;
  const float* Mb = (j < 128) ? M + 16384 : M + 3 * 16384;
  float s = 0.f;
  for (int t = 0; t < 128; ++t)
    s += b_s[t] * Ma[t * 128 + jj] + b_c[t] * Mb[t * 128 + jj];
  gvec[j] = s;
}

// ---------------- tail MFMA GEMM: out = V @ Gt^T + gvec ----------------
__global__ __launch_bounds__(64)
void tail_gemm(const ushort* __restrict__ V, const ushort* __restrict__ Gt,
               const float* __restrict__ gvec, float* __restrict__ out) {
  int lane = threadIdx.x;
  int l15 = lane & 15, lhi = lane >> 4;
  int rowW = blockIdx.x * 16;
  f32x4 acc[16];
  #pragma unroll
  for (int t = 0; t < 16; ++t) acc[t] = (f32x4){0.f, 0.f, 0.f, 0.f};
  const ushort* vp = V + (size_t)(rowW + l15) * KT + lhi * 8;
  const ushort* gp = Gt + (size_t)l15 * KT + lhi * 8;
  #pragma unroll
  for (int ks = 0; ks < 16; ++ks) {
    bf16x8 a = *reinterpret_cast<const bf16x8*>(vp + ks * 32);
    #pragma unroll
    for (int t = 0; t < 16; ++t) {
      bf16x8 b = *reinterpret_cast<const bf16x8*>(gp + (size_t)t * 16 * KT + ks * 32);
      acc[t] = __builtin_amdgcn_mfma_f32_16x16x32_bf16(a, b, acc[t], 0, 0, 0);
    }
  }
  int r0 = rowW + lhi * 4;
  #pragma unroll
  for (int t = 0; t < 16; ++t) {
    int col = t * 16 + l15;
    float gv = gvec[col];
    float* dst = (col < 128) ? out + (size_t)r0 * OUTD + col
                             : out + (size_t)cN2 * OUTD + (size_t)r0 * OUTD + (col - 128);
    #pragma unroll
    for (int r = 0; r < 4; ++r)
      dst[(size_t)r * OUTD] = acc[t][r] + gv;
  }
}

// ---------------- launch ----------------
extern "C" void kernel_launch(void* const* d_in, const int* in_sizes, int n_in,
                              void* d_out, int out_size, void* d_ws, size_t ws_size,
                              hipStream_t stream) {
  const int* x = (const int*)d_in[0];
  struct Branch {
    const int *e0s, *e0d, *e1s, *e1d;
    const float *t0, *t1, *t2, *t3, *t4, *Win, *bin, *Wout, *bout;
  };
  auto mk = [&](int b) {
    Branch B;
    B.e0s = (const int*)d_in[b + 0];
    B.e0d = (const int*)d_in[b + 1];
    B.e1s = (const int*)d_in[b + 2];
    B.e1d = (const int*)d_in[b + 3];
    B.t0  = (const float*)d_in[b + 4];
    B.t1  = (const float*)d_in[b + 5];
    B.t2  = (const float*)d_in[b + 6];
    B.t3  = (const float*)d_in[b + 7];
    B.t4  = (const float*)d_in[b + 8];
    B.Win = (const float*)d_in[b + 9];
    B.bin = (const float*)d_in[b + 10];
    B.Wout= (const float*)d_in[b + 11];
    B.bout= (const float*)d_in[b + 12];
    return B;
  };
  Branch SB = mk(1), CB = mk(14);
  const float* Ws2c = (const float*)d_in[27];
  const float* Wc2s = (const float*)d_in[28];
  const float* a1p  = (const float*)d_in[29];
  const float* a2p  = (const float*)d_in[30];
  const float* b2p  = (const float*)d_in[31];

  // workspace layout (px/btab alias V region — V written only in agg1)
  char* ws = (char*)d_ws;
  ushort* u    = (ushort*)(ws + 0);            // 32,030,720
  ushort* h1   = (ushort*)(ws + 32030720);     // 51,200,000
  ushort* V    = (ushort*)(ws + 83230720);     // 10,240,000
  u64*   px    = (u64*)   (ws + 83230720);     // 1,600,000 (alias V)
  ushort* btab = (ushort*)(ws + 84830720);     // 576,000 (alias V)
  float*  M    = (float*) (ws + 93470720);     // 262,144
  ushort* Gt   = (ushort*)(ws + 93732864);     // 262,144
  float*  gvec = (float*) (ws + 93995008);     // 1,024
  ushort* Wt   = (ushort*)(ws + 93996032);     // 163,840
  int*   bfill = (int*)   (ws + 94159872);     // 1878*4 (pad to 7,680)
  u64*   packed= (u64*)   (ws + 94167552);     // 19,230,720 (end ~113.4MB)

  hipMemsetAsync(bfill, 0, NFILL * sizeof(int), stream);

  pack_x<<<(cN0 + 255) / 256, 256, 0, stream>>>(x, px);
  build_btab<<<2048, 144, 0, stream>>>(
      SB.t0, SB.t1, SB.t2, SB.t3, SB.t4,
      CB.t0, CB.t1, CB.t2, CB.t3, CB.t4, btab);
  build_wt2<<<512, KP, 0, stream>>>(SB.Win, CB.Win, SB.bin, CB.bin, Wt);
  build_small<<<128, 128, 0, stream>>>(Ws2c, Wc2s, a1p, a2p, b2p, M);
  build_G<<<512, 256, 0, stream>>>(SB.Wout, CB.Wout, M, Gt);
  build_gvec<<<1, 256, 0, stream>>>(SB.bout, CB.bout, M, gvec);

  bucketize_v7<<<2 * NCH0 + 2 * NCH1, 512, 0, stream>>>(
      SB.e0s, SB.e0d, CB.e0s, CB.e0d, SB.e1s, SB.e1d, CB.e1s, CB.e1d,
      px, bfill, packed);

  agg0_fused<<<2 * NBA0, 256, 0, stream>>>(px, btab, bfill, packed, u);
  gemm_mfma2<<<4 * GEMM_RB, 256, 0, stream>>>(u, Wt, h1);
  agg1_fused<<<2 * NBA1, 256, 0, stream>>>(h1, bfill, packed, V);
  tail_gemm<<<TAIL_NB, 64, 0, stream>>>(V, Gt, gvec, (float*)d_out);
}

// Round 18
// 219.955 us; speedup vs baseline: 1.4020x; 1.2787x over previous
//
#include <hip/hip_runtime.h>

// ---------------- problem constants ----------------
constexpr int cN0 = 200000, cN1 = 50000, cN2 = 10000;
constexpr int cE0 = 800000, cE1 = 160000;
constexpr int GD  = 144;
constexpr int KP  = 160;       // padded K for MFMA (col 144 = bias-multiplier lane)
constexpr int HID = 256, OUTD = 128;
constexpr int KT  = 512;

constexpr int WN   = 64, CAP = 1280;
constexpr int NBA0 = (cN1 + WN - 1) / WN;     // 782
constexpr int NBA1 = (cN2 + WN - 1) / WN;     // 157
constexpr int NFILL = 2 * NBA0 + 2 * NBA1;    // 1878
constexpr size_t L1PBASE = (size_t)(2 * NBA0) * CAP;

constexpr int GEMM_RB = (50048 + 255) / 256;  // 196
constexpr int TAIL_NB = cN2 / 16;             // 625
constexpr size_t UPLANE = (size_t)50048 * KP;
constexpr int BT_STRIDE = 144000;
constexpr int CAPH1 = 768;                    // half-bucket cap for agg1 (lambda=512)

constexpr int CHUNK = 4096;
constexpr int NCH0  = (cE0 + CHUNK - 1) / CHUNK; // 196
constexpr int NCH1  = (cE1 + CHUNK - 1) / CHUNK; // 40

// prep1 grid regions
constexpr int P1_PACK = (cN0 + 255) / 256;         // 782
constexpr int P1_BTAB = (288000 + 255) / 256;      // 1125
constexpr int P1_WT   = (81920 + 255) / 256;       // 320
constexpr int P1_SMALL = 128;
constexpr int P1_TOT  = P1_PACK + P1_BTAB + P1_WT + P1_SMALL;

typedef __attribute__((ext_vector_type(8))) short bf16x8;
typedef __attribute__((ext_vector_type(4))) float f32x4;
typedef unsigned long long u64;
constexpr u64 PXMASK = (1ull << 50) - 1;

__device__ __forceinline__ ushort f2bf(float f) {
  union { float f; unsigned u; } v; v.f = f;
  unsigned r = (v.u + 0x7FFFu + ((v.u >> 16) & 1u)) >> 16;
  return (ushort)r;
}
__device__ __forceinline__ float bf2f(ushort u) {
  union { unsigned u; float f; } v; v.u = ((unsigned)u) << 16;
  return v.f;
}
__device__ __forceinline__ float bflo(unsigned v) {
  union { unsigned u; float f; } x; x.u = v << 16; return x.f;
}
__device__ __forceinline__ float bfhi(unsigned v) {
  union { unsigned u; float f; } x; x.u = v & 0xFFFF0000u; return x.f;
}

// ---------------- prep1: pack_x + bfill-zero + btab + Wt + M ---------------
__global__ __launch_bounds__(256)
void prep1(const int* __restrict__ x,
           const float* __restrict__ s_t0, const float* __restrict__ s_t1,
           const float* __restrict__ s_t2, const float* __restrict__ s_t3,
           const float* __restrict__ s_t4,
           const float* __restrict__ c_t0, const float* __restrict__ c_t1,
           const float* __restrict__ c_t2, const float* __restrict__ c_t3,
           const float* __restrict__ c_t4,
           const float* __restrict__ Ws, const float* __restrict__ Wc,
           const float* __restrict__ bs, const float* __restrict__ bc,
           const float* __restrict__ Ws2c, const float* __restrict__ Wc2s,
           const float* __restrict__ a1p, const float* __restrict__ a2p,
           const float* __restrict__ b2p,
           u64* __restrict__ px, int* __restrict__ bfill,
           ushort* __restrict__ btab, ushort* __restrict__ Wt,
           float* __restrict__ M) {
  int bid = blockIdx.x, tid = threadIdx.x;
  if (bid < P1_PACK) {
    int i = bid * 256 + tid;
    if (i < NFILL) bfill[i] = 0;
    if (i < cN0) {
      const int* xp = x + (size_t)i * 5;
      u64 v = (u64)(xp[0] & 1023)
            | ((u64)(xp[1] & 1023) << 10)
            | ((u64)(xp[2] & 1023) << 20)
            | ((u64)(xp[3] & 1023) << 30)
            | ((u64)(xp[4] & 1023) << 40);
      px[i] = v;
    }
  } else if (bid < P1_PACK + P1_BTAB) {
    int idx = (bid - P1_PACK) * 256 + tid;
    if (idx < 288000) {
      int br = idx / 144000;
      int rem = idx - br * 144000;
      int row = rem / 144, j = rem - row * 144;
      const float* t; int col, off, dim;
      if (j < 32)      { t = br ? c_t0 : s_t0; col = j;      off = 0;     dim = 32; }
      else if (j < 48) { t = br ? c_t1 : s_t1; col = j - 32; off = 32000; dim = 16; }
      else if (j < 64) { t = br ? c_t2 : s_t2; col = j - 48; off = 48000; dim = 16; }
      else if (j < 80) { t = br ? c_t3 : s_t3; col = j - 64; off = 64000; dim = 16; }
      else             { t = br ? c_t4 : s_t4; col = j - 80; off = 80000; dim = 64; }
      btab[(size_t)br * BT_STRIDE + off + row * dim + col] =
          f2bf(t[(size_t)row * dim + col]);
    }
  } else if (bid < P1_PACK + P1_BTAB + P1_WT) {
    int idx = (bid - P1_PACK - P1_BTAB) * 256 + tid;
    if (idx < 81920) {
      int br = idx / 40960;
      int rem = idx - br * 40960;
      int n = rem / 160, k = rem - n * 160;
      const float* W = br ? Wc : Ws;
      const float* b = br ? bc : bs;
      float v = (k < GD) ? W[(size_t)k * HID + n] : ((k == GD) ? b[n] : 0.f);
      Wt[(size_t)br * HID * KP + n * KP + k] = f2bf(v);
    }
  } else {
    int r = bid - P1_PACK - P1_BTAB - P1_WT;   // 0..127
    if (tid < 128) {
      int c = tid;
      float A1 = a1p[0], A2 = a2p[0], B2 = b2p[0];
      float c0 = 1.f - A2 - B2;
      float c1 = A2 + B2 * (1.f - A1);
      float c2 = A1 * B2;
      float s1 = 0.f, s4 = 0.f;
      for (int k = 0; k < 128; ++k) {
        s1 += Ws2c[r * 128 + k] * Wc2s[k * 128 + c];
        s4 += Wc2s[r * 128 + k] * Ws2c[k * 128 + c];
      }
      float eye = (r == c) ? c0 : 0.f;
      M[0 * 16384 + r * 128 + c] = c2 * s1 + eye;
      M[1 * 16384 + r * 128 + c] = c1 * Wc2s[r * 128 + c];
      M[2 * 16384 + r * 128 + c] = c1 * Ws2c[r * 128 + c];
      M[3 * 16384 + r * 128 + c] = c2 * s4 + eye;
    }
  }
}

// ---------------- prep2: build_G + build_gvec (depends on M) ---------------
__global__ __launch_bounds__(256)
void prep2(const float* __restrict__ Wout_s, const float* __restrict__ Wout_c,
           const float* __restrict__ b_s, const float* __restrict__ b_c,
           const float* __restrict__ M,
           ushort* __restrict__ Gt, float* __restrict__ gvec) {
  __shared__ float wr[128];
  int k = blockIdx.x, j = threadIdx.x;
  if (k < 512) {
    const float* wrow = (k < 256) ? &Wout_s[(size_t)k * 128] : &Wout_c[(size_t)(k - 256) * 128];
    if (j < 128) wr[j] = wrow[j];
    __syncthreads();
    const float* Mm = (j < 128) ? (k < 256 ? M : M + 16384)
                                : (k < 256 ? M + 2 * 16384 : M + 3 * 16384);
    int jj = j & 127;
    float s = 0.f;
    for (int t = 0; t < 128; ++t) s += wr[t] * Mm[t * 128 + jj];
    Gt[(size_t)j * KT + k] = f2bf(s);
  } else {
    int jj = j & 127;
    const float* Ma = (j < 128) ? M : M + 2 * 16384;
    const float* Mb = (j < 128) ? M + 16384 : M + 3 * 16384;
    float s = 0.f;
    for (int t = 0; t < 128; ++t)
      s += b_s[t] * Ma[t * 128 + jj] + b_c[t] * Mb[t * 128 + jj];
    gvec[j] = s;
  }
}

// ---------------- bucketize v7 (unchanged) ----------------
__global__ __launch_bounds__(512)
void bucketize_v7(const int* __restrict__ s0, const int* __restrict__ d0,
                  const int* __restrict__ s1, const int* __restrict__ d1,
                  const int* __restrict__ s2, const int* __restrict__ d2,
                  const int* __restrict__ s3, const int* __restrict__ d3,
                  const u64* __restrict__ px,
                  int* __restrict__ bfill, u64* __restrict__ packed) {
  __shared__ ushort rawD[CHUNK];
  __shared__ u64 sed[CHUNK];
  __shared__ int lcnt[NBA0], lstart[NBA0], gbase_s[NBA0], lfill[NBA0];
  int bid = blockIdx.x, tid = threadIdx.x;
  const int *sp, *dp; int E, blk, NB, fbase, isL0;
  u64* pb;
  if (bid < NCH0) {
    sp = s0; dp = d0; E = cE0; blk = bid;             NB = NBA0;
    fbase = 0;               pb = packed; isL0 = 1;
  } else if (bid < 2 * NCH0) {
    sp = s1; dp = d1; E = cE0; blk = bid - NCH0;      NB = NBA0;
    fbase = NBA0;            pb = packed + (size_t)NBA0 * CAP; isL0 = 1;
  } else if (bid < 2 * NCH0 + NCH1) {
    sp = s2; dp = d2; E = cE1; blk = bid - 2 * NCH0;  NB = NBA1;
    fbase = 2 * NBA0;        pb = packed + L1PBASE; isL0 = 0;
  } else {
    sp = s3; dp = d3; E = cE1; blk = bid - 2 * NCH0 - NCH1; NB = NBA1;
    fbase = 2 * NBA0 + NBA1; pb = packed + L1PBASE + (size_t)NBA1 * CAP; isL0 = 0;
  }
  int base = blk * CHUNK;
  int n = min(CHUNK, E - base);

  for (int i = tid; i < NB; i += 512) { lcnt[i] = 0; lfill[i] = 0; }
  __syncthreads();
  {
    int dds[8];
    #pragma unroll
    for (int k = 0; k < 8; ++k) {
      int i = tid + k * 512;
      dds[k] = (i < n) ? dp[base + i] : -1;
    }
    #pragma unroll
    for (int k = 0; k < 8; ++k) {
      int i = tid + k * 512;
      if (i < n) {
        rawD[i] = (ushort)dds[k];
        atomicAdd(&lcnt[dds[k] >> 6], 1);
      }
    }
  }
  __syncthreads();
  if (tid < 64) {
    int lane = tid;
    int i0 = lane * 13;
    int v[13], s = 0;
    #pragma unroll
    for (int j = 0; j < 13; ++j) {
      v[j] = (i0 + j < NB) ? lcnt[i0 + j] : 0;
      s += v[j];
    }
    int tot = s;
    #pragma unroll
    for (int off = 1; off < 64; off <<= 1) {
      int t = __shfl_up(s, off);
      if (lane >= off) s += t;
    }
    int excl = s - tot;
    #pragma unroll
    for (int j = 0; j < 13; ++j) {
      if (i0 + j < NB) lstart[i0 + j] = excl;
      excl += v[j];
    }
  }
  __syncthreads();
  {
    int srcs[8];
    #pragma unroll
    for (int k = 0; k < 8; ++k) {
      int i = tid + k * 512;
      srcs[k] = (i < n) ? sp[base + i] : 0;
    }
    u64 rec[8];
    if (isL0) {
      #pragma unroll
      for (int k = 0; k < 8; ++k) rec[k] = px[srcs[k]];
    } else {
      #pragma unroll
      for (int k = 0; k < 8; ++k) rec[k] = (u64)(unsigned)srcs[k];
    }
    #pragma unroll
    for (int k = 0; k < 8; ++k) {
      int i = tid + k * 512;
      if (i < n) {
        int dd = rawD[i];
        int b = dd >> 6;
        int p = atomicAdd(&lfill[b], 1);
        sed[lstart[b] + p] = rec[k] | ((u64)(unsigned)(dd & 63) << 50);
      }
    }
  }
  __syncthreads();
  for (int b = tid; b < NB; b += 512) {
    int cnt = lcnt[b];
    gbase_s[b] = (cnt > 0) ? atomicAdd(&bfill[fbase + b], cnt) : 0;
  }
  __syncthreads();
  int lane = tid & 63, wv = tid >> 6;
  for (int b = wv; b < NB; b += 8) {
    int cnt = lcnt[b];
    if (cnt == 0) continue;
    int gb0 = gbase_s[b];
    int st = lstart[b];
    for (int i = lane; i < cnt; i += 64) {
      int gp = gb0 + i;
      if (gp < CAP) pb[(size_t)b * CAP + gp] = sed[st + i];
    }
  }
}

// ---------------- fused layer-0 (unchanged from R16) ----------------
__global__ __launch_bounds__(256)
void agg0_fused(const u64* __restrict__ px, const ushort* __restrict__ btab,
                const int* __restrict__ bfill, const u64* __restrict__ packed,
                ushort* __restrict__ u) {
  __shared__ u64 lpx[CAP];
  __shared__ int lcnt[64], lstart[64], lfill[64];
  int tid = threadIdx.x, w = tid >> 6, lane = tid & 63;
  int gb = blockIdx.x;
  int br = gb / NBA0;
  int bk = gb - br * NBA0;
  int dst0 = bk * WN;
  int nd = min(WN, cN1 - dst0);

  const ushort* bt = btab + (size_t)br * BT_STRIDE;
  int sub = lane / 18;
  int g   = lane - sub * 18;
  const ushort* gbase; int sh, gstride;
  if (g < 4)       { gbase = bt + g * 8;              sh = 0;  gstride = 32; }
  else if (g < 6)  { gbase = bt + 32000 + (g - 4) * 8; sh = 10; gstride = 16; }
  else if (g < 8)  { gbase = bt + 48000 + (g - 6) * 8; sh = 20; gstride = 16; }
  else if (g < 10) { gbase = bt + 64000 + (g - 8) * 8; sh = 30; gstride = 16; }
  else             { gbase = bt + 80000 + (g - 10) * 8; sh = 40; gstride = 64; }

  if (tid < 64) { lcnt[tid] = 0; lfill[tid] = 0; }
  __syncthreads();
  int ec = min(bfill[gb], CAP);
  const u64* pb = packed + (size_t)gb * CAP;
  for (int i = tid; i < ec; i += 256)
    atomicAdd(&lcnt[(int)(pb[i] >> 50) & 63], 1);
  __syncthreads();
  if (tid < 64) {
    int c = lcnt[tid]; int s = c;
    #pragma unroll
    for (int off = 1; off < 64; off <<= 1) {
      int t = __shfl_up(s, off);
      if (lane >= off) s += t;
    }
    lstart[tid] = s - c;
  }
  __syncthreads();
  for (int i = tid; i < ec; i += 256) {
    u64 v = pb[i];
    int l = (int)(v >> 50) & 63;
    int p = atomicAdd(&lfill[l], 1);
    lpx[lstart[l] + p] = v & PXMASK;
  }
  __syncthreads();

  for (int d = w; d < nd; d += 4) {
    int deg = lcnt[d], beg = lstart[d];
    float acc[8];
    #pragma unroll
    for (int j = 0; j < 8; ++j) acc[j] = 0.f;
    int e0 = (sub < 3) ? sub : deg;
    for (int e = e0; e < deg; e += 3) {
      u64 rec = lpx[beg + e];
      int r = (int)((rec >> sh) & 1023ull);
      uint4 gv = *reinterpret_cast<const uint4*>(gbase + (size_t)r * gstride);
      acc[0] += bflo(gv.x); acc[1] += bfhi(gv.x);
      acc[2] += bflo(gv.y); acc[3] += bfhi(gv.y);
      acc[4] += bflo(gv.z); acc[5] += bfhi(gv.z);
      acc[6] += bflo(gv.w); acc[7] += bfhi(gv.w);
    }
    #pragma unroll
    for (int j = 0; j < 8; ++j) {
      float a1 = __shfl(acc[j], lane + 18);
      float a2 = __shfl(acc[j], lane + 36);
      acc[j] += a1 + a2;
    }
    float invc = (deg > 0) ? 1.f / (float)deg : 0.f;
    int dg = dst0 + d;
    ushort* ur = u + (size_t)br * UPLANE + (size_t)dg * KP;
    if (sub == 0) {
      u64 pvd = px[dg];
      int rowd = (int)((pvd >> sh) & 1023ull);
      uint4 sv = *reinterpret_cast<const uint4*>(gbase + (size_t)rowd * gstride);
      float s[8];
      s[0] = bflo(sv.x); s[1] = bfhi(sv.x);
      s[2] = bflo(sv.y); s[3] = bfhi(sv.y);
      s[4] = bflo(sv.z); s[5] = bfhi(sv.z);
      s[6] = bflo(sv.w); s[7] = bfhi(sv.w);
      bf16x8 o;
      #pragma unroll
      for (int j = 0; j < 8; ++j) o[j] = (short)f2bf(s[j] + acc[j] * invc);
      *reinterpret_cast<bf16x8*>(ur + g * 8) = o;
    } else if (lane == 18) {
      bf16x8 o = (bf16x8){0, 0, 0, 0, 0, 0, 0, 0};
      o[0] = (short)f2bf(deg > 0 ? 2.f : 1.f);
      *reinterpret_cast<bf16x8*>(ur + 144) = o;
    } else if (lane == 19) {
      *reinterpret_cast<bf16x8*>(ur + 152) = (bf16x8){0, 0, 0, 0, 0, 0, 0, 0};
    }
  }
}

// ---------------- layer-0 MFMA GEMM (unchanged) ----------------
__global__ __launch_bounds__(256)
void gemm_mfma2(const ushort* __restrict__ U, const ushort* __restrict__ Wt,
                ushort* __restrict__ h1) {
  __shared__ ushort Wth[128][KP + 8];
  int bid = blockIdx.x, tid = threadIdx.x;
  int rowblk = bid % GEMM_RB;
  int half = (bid / GEMM_RB) & 1;
  int br = bid / (2 * GEMM_RB);
  const ushort* Wsrc = Wt + ((size_t)br * HID + half * 128) * KP;
  for (int i = tid; i < 128 * (KP / 8); i += 256) {
    int r = i / (KP / 8), g = i - r * (KP / 8);
    *reinterpret_cast<bf16x8*>(&Wth[r][g * 8]) =
        *reinterpret_cast<const bf16x8*>(Wsrc + (size_t)r * KP + g * 8);
  }
  __syncthreads();
  int w = tid >> 6, lane = tid & 63, l15 = lane & 15, lhi = lane >> 4;
  int rowbase = rowblk * 256 + w * 64;
  const ushort* Ubr = U + (size_t)br * UPLANE;
  f32x4 acc[4][8];
  #pragma unroll
  for (int rt = 0; rt < 4; ++rt)
    #pragma unroll
    for (int ct = 0; ct < 8; ++ct) acc[rt][ct] = (f32x4){0.f, 0.f, 0.f, 0.f};
  #pragma unroll
  for (int ks = 0; ks < 5; ++ks) {
    bf16x8 bfr[8];
    #pragma unroll
    for (int ct = 0; ct < 8; ++ct)
      bfr[ct] = *reinterpret_cast<const bf16x8*>(&Wth[ct * 16 + l15][lhi * 8 + ks * 32]);
    #pragma unroll
    for (int rt = 0; rt < 4; ++rt) {
      int ar = rowbase + rt * 16 + l15;
      if (ar > 50047) ar = 50047;
      bf16x8 af = *reinterpret_cast<const bf16x8*>(Ubr + (size_t)ar * KP + lhi * 8 + ks * 32);
      #pragma unroll
      for (int ct = 0; ct < 8; ++ct)
        acc[rt][ct] = __builtin_amdgcn_mfma_f32_16x16x32_bf16(af, bfr[ct], acc[rt][ct], 0, 0, 0);
    }
  }
  ushort* h1p = h1 + (size_t)br * cN1 * HID + half * 128;
  #pragma unroll
  for (int rt = 0; rt < 4; ++rt) {
    #pragma unroll
    for (int r = 0; r < 4; ++r) {
      int row = rowbase + rt * 16 + lhi * 4 + r;
      if (row >= cN1) continue;
      #pragma unroll
      for (int ct = 0; ct < 8; ++ct)
        h1p[(size_t)row * HID + ct * 16 + l15] = f2bf(fmaxf(acc[rt][ct][r], 0.f));
    }
  }
}

// ---------------- fused layer-1: half-bucket blocks (32 dsts) --------------
// grid: 2 * (2*NBA1) = 628 blocks of 256 threads.
__global__ __launch_bounds__(256)
void agg1_fused(const ushort* __restrict__ h1, const int* __restrict__ bfill,
                const u64* __restrict__ packed, ushort* __restrict__ V) {
  __shared__ int lsrc[CAPH1];
  __shared__ int lcnt[32], lstart[32], lfill[32];
  int tid = threadIdx.x, w = tid >> 6, lane = tid & 63;
  int gbFull = blockIdx.x >> 1;
  int h = blockIdx.x & 1;
  int br = gbFull / NBA1;
  int bk = gbFull - br * NBA1;
  int fb = 2 * NBA0 + gbFull;
  int dst0 = bk * WN + h * 32;
  int nd = min(32, cN2 - dst0);
  if (nd <= 0) return;
  const ushort* h1p = h1 + (size_t)br * cN1 * HID;

  if (tid < 32) { lcnt[tid] = 0; lfill[tid] = 0; }
  __syncthreads();
  int ec = min(bfill[fb], CAP);
  const u64* pb = packed + L1PBASE + (size_t)gbFull * CAP;
  // pass A: count (own half: dst bit 5)
  for (int i = tid; i < ec; i += 256) {
    unsigned ldst = (unsigned)(pb[i] >> 50) & 63u;
    if ((int)(ldst >> 5) == h) atomicAdd(&lcnt[ldst & 31u], 1);
  }
  __syncthreads();
  if (tid < 32) {
    int c = lcnt[tid]; int s = c;
    #pragma unroll
    for (int off = 1; off < 32; off <<= 1) {
      int t = __shfl_up(s, off);
      if (tid >= off) s += t;
    }
    lstart[tid] = s - c;
  }
  __syncthreads();
  // pass B: scatter src by dst (own half)
  for (int i = tid; i < ec; i += 256) {
    u64 v = pb[i];
    unsigned ldst = (unsigned)(v >> 50) & 63u;
    if ((int)(ldst >> 5) == h) {
      int l = (int)(ldst & 31u);
      int p = atomicAdd(&lfill[l], 1);
      int idx = lstart[l] + p;
      if (idx < CAPH1) lsrc[idx] = (int)(v & 0x3FFFFull);
    }
  }
  __syncthreads();

  for (int d = w; d < nd; d += 4) {
    int deg = lcnt[d], beg = lstart[d];
    float4 acc = make_float4(0.f, 0.f, 0.f, 0.f);
    int e = 0;
    for (; e + 4 <= deg; e += 4) {
      int sA = lsrc[beg + e], sB = lsrc[beg + e + 1];
      int sC = lsrc[beg + e + 2], sD = lsrc[beg + e + 3];
      ushort4 hA = *reinterpret_cast<const ushort4*>(h1p + (size_t)sA * HID + lane * 4);
      ushort4 hB = *reinterpret_cast<const ushort4*>(h1p + (size_t)sB * HID + lane * 4);
      ushort4 hC = *reinterpret_cast<const ushort4*>(h1p + (size_t)sC * HID + lane * 4);
      ushort4 hD = *reinterpret_cast<const ushort4*>(h1p + (size_t)sD * HID + lane * 4);
      acc.x += bf2f(hA.x) + bf2f(hB.x) + bf2f(hC.x) + bf2f(hD.x);
      acc.y += bf2f(hA.y) + bf2f(hB.y) + bf2f(hC.y) + bf2f(hD.y);
      acc.z += bf2f(hA.z) + bf2f(hB.z) + bf2f(hC.z) + bf2f(hD.z);
      acc.w += bf2f(hA.w) + bf2f(hB.w) + bf2f(hC.w) + bf2f(hD.w);
    }
    for (; e < deg; ++e) {
      int s = lsrc[beg + e];
      ushort4 hv = *reinterpret_cast<const ushort4*>(h1p + (size_t)s * HID + lane * 4);
      acc.x += bf2f(hv.x); acc.y += bf2f(hv.y); acc.z += bf2f(hv.z); acc.w += bf2f(hv.w);
    }
    float invc = (deg > 0) ? 1.f / (float)deg : 0.f;
    int dg = dst0 + d;
    ushort4 dv = *reinterpret_cast<const ushort4*>(h1p + (size_t)dg * HID + lane * 4);
    ushort4 o;
    o.x = f2bf(bf2f(dv.x) + acc.x * invc);
    o.y = f2bf(bf2f(dv.y) + acc.y * invc);
    o.z = f2bf(bf2f(dv.z) + acc.z * invc);
    o.w = f2bf(bf2f(dv.w) + acc.w * invc);
    *reinterpret_cast<ushort4*>(V + (size_t)dg * KT + br * HID + lane * 4) = o;
  }
}

// ---------------- tail MFMA GEMM: K-split across 2 waves ----------------
__global__ __launch_bounds__(128)
void tail_gemm(const ushort* __restrict__ V, const ushort* __restrict__ Gt,
               const float* __restrict__ gvec, float* __restrict__ out) {
  __shared__ f32x4 red[16][64];     // 16 KB
  int tid = threadIdx.x;
  int wv = tid >> 6, lane = tid & 63;
  int l15 = lane & 15, lhi = lane >> 4;
  int rowW = blockIdx.x * 16;
  f32x4 acc[16];
  #pragma unroll
  for (int t = 0; t < 16; ++t) acc[t] = (f32x4){0.f, 0.f, 0.f, 0.f};
  const ushort* vp = V + (size_t)(rowW + l15) * KT + lhi * 8 + wv * 256;
  const ushort* gp = Gt + (size_t)l15 * KT + lhi * 8 + wv * 256;
  #pragma unroll
  for (int ks = 0; ks < 8; ++ks) {
    bf16x8 a = *reinterpret_cast<const bf16x8*>(vp + ks * 32);
    #pragma unroll
    for (int t = 0; t < 16; ++t) {
      bf16x8 b = *reinterpret_cast<const bf16x8*>(gp + (size_t)t * 16 * KT + ks * 32);
      acc[t] = __builtin_amdgcn_mfma_f32_16x16x32_bf16(a, b, acc[t], 0, 0, 0);
    }
  }
  if (wv == 1) {
    #pragma unroll
    for (int t = 0; t < 16; ++t) red[t][lane] = acc[t];
  }
  __syncthreads();
  if (wv == 0) {
    int r0 = rowW + lhi * 4;
    #pragma unroll
    for (int t = 0; t < 16; ++t) {
      f32x4 o = acc[t] + red[t][lane];
      int col = t * 16 + l15;
      float gv = gvec[col];
      float* dst = (col < 128) ? out + (size_t)r0 * OUTD + col
                               : out + (size_t)cN2 * OUTD + (size_t)r0 * OUTD + (col - 128);
      #pragma unroll
      for (int r = 0; r < 4; ++r)
        dst[(size_t)r * OUTD] = o[r] + gv;
    }
  }
}

// ---------------- launch ----------------
extern "C" void kernel_launch(void* const* d_in, const int* in_sizes, int n_in,
                              void* d_out, int out_size, void* d_ws, size_t ws_size,
                              hipStream_t stream) {
  const int* x = (const int*)d_in[0];
  struct Branch {
    const int *e0s, *e0d, *e1s, *e1d;
    const float *t0, *t1, *t2, *t3, *t4, *Win, *bin, *Wout, *bout;
  };
  auto mk = [&](int b) {
    Branch B;
    B.e0s = (const int*)d_in[b + 0];
    B.e0d = (const int*)d_in[b + 1];
    B.e1s = (const int*)d_in[b + 2];
    B.e1d = (const int*)d_in[b + 3];
    B.t0  = (const float*)d_in[b + 4];
    B.t1  = (const float*)d_in[b + 5];
    B.t2  = (const float*)d_in[b + 6];
    B.t3  = (const float*)d_in[b + 7];
    B.t4  = (const float*)d_in[b + 8];
    B.Win = (const float*)d_in[b + 9];
    B.bin = (const float*)d_in[b + 10];
    B.Wout= (const float*)d_in[b + 11];
    B.bout= (const float*)d_in[b + 12];
    return B;
  };
  Branch SB = mk(1), CB = mk(14);
  const float* Ws2c = (const float*)d_in[27];
  const float* Wc2s = (const float*)d_in[28];
  const float* a1p  = (const float*)d_in[29];
  const float* a2p  = (const float*)d_in[30];
  const float* b2p  = (const float*)d_in[31];

  // workspace layout (px/btab alias V region — V written only in agg1)
  char* ws = (char*)d_ws;
  ushort* u    = (ushort*)(ws + 0);            // 32,030,720
  ushort* h1   = (ushort*)(ws + 32030720);     // 51,200,000
  ushort* V    = (ushort*)(ws + 83230720);     // 10,240,000
  u64*   px    = (u64*)   (ws + 83230720);     // 1,600,000 (alias V)
  ushort* btab = (ushort*)(ws + 84830720);     // 576,000 (alias V)
  float*  M    = (float*) (ws + 93470720);     // 262,144
  ushort* Gt   = (ushort*)(ws + 93732864);     // 262,144
  float*  gvec = (float*) (ws + 93995008);     // 1,024
  ushort* Wt   = (ushort*)(ws + 93996032);     // 163,840
  int*   bfill = (int*)   (ws + 94159872);     // 1878*4 (pad to 7,680)
  u64*   packed= (u64*)   (ws + 94167552);     // 19,230,720 (end ~113.4MB)

  // prep1: pack_x + bfill-zero + btab + Wt + M (all independent)
  prep1<<<P1_TOT, 256, 0, stream>>>(x,
      SB.t0, SB.t1, SB.t2, SB.t3, SB.t4,
      CB.t0, CB.t1, CB.t2, CB.t3, CB.t4,
      SB.Win, CB.Win, SB.bin, CB.bin,
      Ws2c, Wc2s, a1p, a2p, b2p,
      px, bfill, btab, Wt, M);
  // prep2: Gt + gvec (depend on M)
  prep2<<<513, 256, 0, stream>>>(SB.Wout, CB.Wout, SB.bout, CB.bout, M, Gt, gvec);

  bucketize_v7<<<2 * NCH0 + 2 * NCH1, 512, 0, stream>>>(
      SB.e0s, SB.e0d, CB.e0s, CB.e0d, SB.e1s, SB.e1d, CB.e1s, CB.e1d,
      px, bfill, packed);

  agg0_fused<<<2 * NBA0, 256, 0, stream>>>(px, btab, bfill, packed, u);
  gemm_mfma2<<<4 * GEMM_RB, 256, 0, stream>>>(u, Wt, h1);
  agg1_fused<<<4 * NBA1, 256, 0, stream>>>(h1, bfill, packed, V);
  tail_gemm<<<TAIL_NB, 128, 0, stream>>>(V, Gt, gvec, (float*)d_out);
}

// Round 19
// 216.239 us; speedup vs baseline: 1.4261x; 1.0172x over previous
//
#include <hip/hip_runtime.h>

// ---------------- problem constants ----------------
constexpr int cN0 = 200000, cN1 = 50000, cN2 = 10000;
constexpr int cE0 = 800000, cE1 = 160000;
constexpr int GD  = 144;
constexpr int KP  = 160;       // padded K for MFMA (col 144 = bias-multiplier lane)
constexpr int HID = 256, OUTD = 128;
constexpr int KT  = 512;

constexpr int WN   = 64, CAP = 1280;
constexpr int NBA0 = (cN1 + WN - 1) / WN;     // 782
constexpr int NBA1 = (cN2 + WN - 1) / WN;     // 157
constexpr int NFILL = 2 * NBA0 + 2 * NBA1;    // 1878
constexpr size_t L1PBASE = (size_t)(2 * NBA0) * CAP;

constexpr int GEMM_RB = (50048 + 255) / 256;  // 196
constexpr int TAIL_NB = cN2 / 16;             // 625
constexpr size_t UPLANE = (size_t)50048 * KP;
constexpr int BT_STRIDE = 144000;
constexpr int CAPH1 = 768;

constexpr int CHUNK = 4096;
constexpr int NCH0  = (cE0 + CHUNK - 1) / CHUNK; // 196
constexpr int NCH1  = (cE1 + CHUNK - 1) / CHUNK; // 40

// prep1 grid regions
constexpr int P1_PACK = (cN0 + 255) / 256;         // 782
constexpr int P1_BTAB = (288000 + 255) / 256;      // 1125
constexpr int P1_WT   = (81920 + 255) / 256;       // 320
constexpr int P1_SMALL = 128;
constexpr int P1_TOT  = P1_PACK + P1_BTAB + P1_WT + P1_SMALL;

typedef __attribute__((ext_vector_type(8))) short bf16x8;
typedef __attribute__((ext_vector_type(4))) float f32x4;
typedef unsigned long long u64;
constexpr u64 PXMASK = (1ull << 50) - 1;

__device__ __forceinline__ ushort f2bf(float f) {
  union { float f; unsigned u; } v; v.f = f;
  unsigned r = (v.u + 0x7FFFu + ((v.u >> 16) & 1u)) >> 16;
  return (ushort)r;
}
__device__ __forceinline__ float bf2f(ushort u) {
  union { unsigned u; float f; } v; v.u = ((unsigned)u) << 16;
  return v.f;
}
__device__ __forceinline__ float bflo(unsigned v) {
  union { unsigned u; float f; } x; x.u = v << 16; return x.f;
}
__device__ __forceinline__ float bfhi(unsigned v) {
  union { unsigned u; float f; } x; x.u = v & 0xFFFF0000u; return x.f;
}

// ---------------- prep1: pack_x + bfill-zero + btab + Wt + M ---------------
__global__ __launch_bounds__(256)
void prep1(const int* __restrict__ x,
           const float* __restrict__ s_t0, const float* __restrict__ s_t1,
           const float* __restrict__ s_t2, const float* __restrict__ s_t3,
           const float* __restrict__ s_t4,
           const float* __restrict__ c_t0, const float* __restrict__ c_t1,
           const float* __restrict__ c_t2, const float* __restrict__ c_t3,
           const float* __restrict__ c_t4,
           const float* __restrict__ Ws, const float* __restrict__ Wc,
           const float* __restrict__ bs, const float* __restrict__ bc,
           const float* __restrict__ Ws2c, const float* __restrict__ Wc2s,
           const float* __restrict__ a1p, const float* __restrict__ a2p,
           const float* __restrict__ b2p,
           u64* __restrict__ px, int* __restrict__ bfill,
           ushort* __restrict__ btab, ushort* __restrict__ Wt,
           float* __restrict__ M) {
  int bid = blockIdx.x, tid = threadIdx.x;
  if (bid < P1_PACK) {
    int i = bid * 256 + tid;
    if (i < NFILL) bfill[i] = 0;
    if (i < cN0) {
      const int* xp = x + (size_t)i * 5;
      u64 v = (u64)(xp[0] & 1023)
            | ((u64)(xp[1] & 1023) << 10)
            | ((u64)(xp[2] & 1023) << 20)
            | ((u64)(xp[3] & 1023) << 30)
            | ((u64)(xp[4] & 1023) << 40);
      px[i] = v;
    }
  } else if (bid < P1_PACK + P1_BTAB) {
    int idx = (bid - P1_PACK) * 256 + tid;
    if (idx < 288000) {
      int br = idx / 144000;
      int rem = idx - br * 144000;
      int row = rem / 144, j = rem - row * 144;
      const float* t; int col, off, dim;
      if (j < 32)      { t = br ? c_t0 : s_t0; col = j;      off = 0;     dim = 32; }
      else if (j < 48) { t = br ? c_t1 : s_t1; col = j - 32; off = 32000; dim = 16; }
      else if (j < 64) { t = br ? c_t2 : s_t2; col = j - 48; off = 48000; dim = 16; }
      else if (j < 80) { t = br ? c_t3 : s_t3; col = j - 64; off = 64000; dim = 16; }
      else             { t = br ? c_t4 : s_t4; col = j - 80; off = 80000; dim = 64; }
      btab[(size_t)br * BT_STRIDE + off + row * dim + col] =
          f2bf(t[(size_t)row * dim + col]);
    }
  } else if (bid < P1_PACK + P1_BTAB + P1_WT) {
    int idx = (bid - P1_PACK - P1_BTAB) * 256 + tid;
    if (idx < 81920) {
      int br = idx / 40960;
      int rem = idx - br * 40960;
      int n = rem / 160, k = rem - n * 160;
      const float* W = br ? Wc : Ws;
      const float* b = br ? bc : bs;
      float v = (k < GD) ? W[(size_t)k * HID + n] : ((k == GD) ? b[n] : 0.f);
      Wt[(size_t)br * HID * KP + n * KP + k] = f2bf(v);
    }
  } else {
    int r = bid - P1_PACK - P1_BTAB - P1_WT;   // 0..127
    if (tid < 128) {
      int c = tid;
      float A1 = a1p[0], A2 = a2p[0], B2 = b2p[0];
      float c0 = 1.f - A2 - B2;
      float c1 = A2 + B2 * (1.f - A1);
      float c2 = A1 * B2;
      float s1 = 0.f, s4 = 0.f;
      for (int k = 0; k < 128; ++k) {
        s1 += Ws2c[r * 128 + k] * Wc2s[k * 128 + c];
        s4 += Wc2s[r * 128 + k] * Ws2c[k * 128 + c];
      }
      float eye = (r == c) ? c0 : 0.f;
      M[0 * 16384 + r * 128 + c] = c2 * s1 + eye;
      M[1 * 16384 + r * 128 + c] = c1 * Wc2s[r * 128 + c];
      M[2 * 16384 + r * 128 + c] = c1 * Ws2c[r * 128 + c];
      M[3 * 16384 + r * 128 + c] = c2 * s4 + eye;
    }
  }
}

// ---------------- prep2: build_G + build_gvec (depends on M) ---------------
__global__ __launch_bounds__(256)
void prep2(const float* __restrict__ Wout_s, const float* __restrict__ Wout_c,
           const float* __restrict__ b_s, const float* __restrict__ b_c,
           const float* __restrict__ M,
           ushort* __restrict__ Gt, float* __restrict__ gvec) {
  __shared__ float wr[128];
  int k = blockIdx.x, j = threadIdx.x;
  if (k < 512) {
    const float* wrow = (k < 256) ? &Wout_s[(size_t)k * 128] : &Wout_c[(size_t)(k - 256) * 128];
    if (j < 128) wr[j] = wrow[j];
    __syncthreads();
    const float* Mm = (j < 128) ? (k < 256 ? M : M + 16384)
                                : (k < 256 ? M + 2 * 16384 : M + 3 * 16384);
    int jj = j & 127;
    float s = 0.f;
    for (int t = 0; t < 128; ++t) s += wr[t] * Mm[t * 128 + jj];
    Gt[(size_t)j * KT + k] = f2bf(s);
  } else {
    int jj = j & 127;
    const float* Ma = (j < 128) ? M : M + 2 * 16384;
    const float* Mb = (j < 128) ? M + 16384 : M + 3 * 16384;
    float s = 0.f;
    for (int t = 0; t < 128; ++t)
      s += b_s[t] * Ma[t * 128 + jj] + b_c[t] * Mb[t * 128 + jj];
    gvec[j] = s;
  }
}

// ---------------- bucketize v8: int4 edge loads ----------------
__global__ __launch_bounds__(512)
void bucketize_v8(const int* __restrict__ s0, const int* __restrict__ d0,
                  const int* __restrict__ s1, const int* __restrict__ d1,
                  const int* __restrict__ s2, const int* __restrict__ d2,
                  const int* __restrict__ s3, const int* __restrict__ d3,
                  const u64* __restrict__ px,
                  int* __restrict__ bfill, u64* __restrict__ packed) {
  __shared__ ushort rawD[CHUNK];
  __shared__ u64 sed[CHUNK];
  __shared__ int lcnt[NBA0], lstart[NBA0], gbase_s[NBA0], lfill[NBA0];
  int bid = blockIdx.x, tid = threadIdx.x;
  const int *sp, *dp; int E, blk, NB, fbase, isL0;
  u64* pb;
  if (bid < NCH0) {
    sp = s0; dp = d0; E = cE0; blk = bid;             NB = NBA0;
    fbase = 0;               pb = packed; isL0 = 1;
  } else if (bid < 2 * NCH0) {
    sp = s1; dp = d1; E = cE0; blk = bid - NCH0;      NB = NBA0;
    fbase = NBA0;            pb = packed + (size_t)NBA0 * CAP; isL0 = 1;
  } else if (bid < 2 * NCH0 + NCH1) {
    sp = s2; dp = d2; E = cE1; blk = bid - 2 * NCH0;  NB = NBA1;
    fbase = 2 * NBA0;        pb = packed + L1PBASE; isL0 = 0;
  } else {
    sp = s3; dp = d3; E = cE1; blk = bid - 2 * NCH0 - NCH1; NB = NBA1;
    fbase = 2 * NBA0 + NBA1; pb = packed + L1PBASE + (size_t)NBA1 * CAP; isL0 = 0;
  }
  int base = blk * CHUNK;
  int n = min(CHUNK, E - base);
  bool full = (n == CHUNK);

  for (int i = tid; i < NB; i += 512) { lcnt[i] = 0; lfill[i] = 0; }
  __syncthreads();
  // phase 1: int4-batched dst loads (2x int4/thread), then count
  {
    int dds[8];
    if (full) {
      int4 a = *reinterpret_cast<const int4*>(dp + base + tid * 4);
      int4 b = *reinterpret_cast<const int4*>(dp + base + 2048 + tid * 4);
      dds[0] = a.x; dds[1] = a.y; dds[2] = a.z; dds[3] = a.w;
      dds[4] = b.x; dds[5] = b.y; dds[6] = b.z; dds[7] = b.w;
    } else {
      #pragma unroll
      for (int k = 0; k < 8; ++k) {
        int i = (k < 4) ? tid * 4 + k : 2048 + tid * 4 + (k - 4);
        dds[k] = (i < n) ? dp[base + i] : -1;
      }
    }
    #pragma unroll
    for (int k = 0; k < 8; ++k) {
      int i = (k < 4) ? tid * 4 + k : 2048 + tid * 4 + (k - 4);
      if (i < n) {
        rawD[i] = (ushort)dds[k];
        atomicAdd(&lcnt[dds[k] >> 6], 1);
      }
    }
  }
  __syncthreads();
  // phase 2: single-wave exclusive scan
  if (tid < 64) {
    int lane = tid;
    int i0 = lane * 13;
    int v[13], s = 0;
    #pragma unroll
    for (int j = 0; j < 13; ++j) {
      v[j] = (i0 + j < NB) ? lcnt[i0 + j] : 0;
      s += v[j];
    }
    int tot = s;
    #pragma unroll
    for (int off = 1; off < 64; off <<= 1) {
      int t = __shfl_up(s, off);
      if (lane >= off) s += t;
    }
    int excl = s - tot;
    #pragma unroll
    for (int j = 0; j < 13; ++j) {
      if (i0 + j < NB) lstart[i0 + j] = excl;
      excl += v[j];
    }
  }
  __syncthreads();
  // phase 3: int4-batched src loads (+ px gathers for L0), scatter records
  {
    int srcs[8];
    if (full) {
      int4 a = *reinterpret_cast<const int4*>(sp + base + tid * 4);
      int4 b = *reinterpret_cast<const int4*>(sp + base + 2048 + tid * 4);
      srcs[0] = a.x; srcs[1] = a.y; srcs[2] = a.z; srcs[3] = a.w;
      srcs[4] = b.x; srcs[5] = b.y; srcs[6] = b.z; srcs[7] = b.w;
    } else {
      #pragma unroll
      for (int k = 0; k < 8; ++k) {
        int i = (k < 4) ? tid * 4 + k : 2048 + tid * 4 + (k - 4);
        srcs[k] = (i < n) ? sp[base + i] : 0;
      }
    }
    u64 rec[8];
    if (isL0) {
      #pragma unroll
      for (int k = 0; k < 8; ++k) rec[k] = px[srcs[k]];
    } else {
      #pragma unroll
      for (int k = 0; k < 8; ++k) rec[k] = (u64)(unsigned)srcs[k];
    }
    #pragma unroll
    for (int k = 0; k < 8; ++k) {
      int i = (k < 4) ? tid * 4 + k : 2048 + tid * 4 + (k - 4);
      if (i < n) {
        int dd = rawD[i];
        int b = dd >> 6;
        int p = atomicAdd(&lfill[b], 1);
        sed[lstart[b] + p] = rec[k] | ((u64)(unsigned)(dd & 63) << 50);
      }
    }
  }
  __syncthreads();
  for (int b = tid; b < NB; b += 512) {
    int cnt = lcnt[b];
    gbase_s[b] = (cnt > 0) ? atomicAdd(&bfill[fbase + b], cnt) : 0;
  }
  __syncthreads();
  int lane = tid & 63, wv = tid >> 6;
  for (int b = wv; b < NB; b += 8) {
    int cnt = lcnt[b];
    if (cnt == 0) continue;
    int gb0 = gbase_s[b];
    int st = lstart[b];
    for (int i = lane; i < cnt; i += 64) {
      int gp = gb0 + i;
      if (gp < CAP) pb[(size_t)b * CAP + gp] = sed[st + i];
    }
  }
}

// ---------------- fused layer-0: 18-lane groups, 2-edge unroll -------------
__global__ __launch_bounds__(256)
void agg0_fused(const u64* __restrict__ px, const ushort* __restrict__ btab,
                const int* __restrict__ bfill, const u64* __restrict__ packed,
                ushort* __restrict__ u) {
  __shared__ u64 lpx[CAP];
  __shared__ int lcnt[64], lstart[64], lfill[64];
  int tid = threadIdx.x, w = tid >> 6, lane = tid & 63;
  int gb = blockIdx.x;
  int br = gb / NBA0;
  int bk = gb - br * NBA0;
  int dst0 = bk * WN;
  int nd = min(WN, cN1 - dst0);

  const ushort* bt = btab + (size_t)br * BT_STRIDE;
  int sub = lane / 18;
  int g   = lane - sub * 18;
  const ushort* gbase; int sh, gstride;
  if (g < 4)       { gbase = bt + g * 8;              sh = 0;  gstride = 32; }
  else if (g < 6)  { gbase = bt + 32000 + (g - 4) * 8; sh = 10; gstride = 16; }
  else if (g < 8)  { gbase = bt + 48000 + (g - 6) * 8; sh = 20; gstride = 16; }
  else if (g < 10) { gbase = bt + 64000 + (g - 8) * 8; sh = 30; gstride = 16; }
  else             { gbase = bt + 80000 + (g - 10) * 8; sh = 40; gstride = 64; }

  if (tid < 64) { lcnt[tid] = 0; lfill[tid] = 0; }
  __syncthreads();
  int ec = min(bfill[gb], CAP);
  const u64* pb = packed + (size_t)gb * CAP;
  for (int i = tid; i < ec; i += 256)
    atomicAdd(&lcnt[(int)(pb[i] >> 50) & 63], 1);
  __syncthreads();
  if (tid < 64) {
    int c = lcnt[tid]; int s = c;
    #pragma unroll
    for (int off = 1; off < 64; off <<= 1) {
      int t = __shfl_up(s, off);
      if (lane >= off) s += t;
    }
    lstart[tid] = s - c;
  }
  __syncthreads();
  for (int i = tid; i < ec; i += 256) {
    u64 v = pb[i];
    int l = (int)(v >> 50) & 63;
    int p = atomicAdd(&lfill[l], 1);
    lpx[lstart[l] + p] = v & PXMASK;
  }
  __syncthreads();

  for (int d = w; d < nd; d += 4) {
    int deg = lcnt[d], beg = lstart[d];
    float acc[8];
    #pragma unroll
    for (int j = 0; j < 8; ++j) acc[j] = 0.f;
    if (sub < 3) {
      int e = sub;
      // 2-edge unrolled main loop: edges e and e+3 in flight together
      for (; e + 3 < deg; e += 6) {
        u64 rec1 = lpx[beg + e];
        u64 rec2 = lpx[beg + e + 3];
        int r1 = (int)((rec1 >> sh) & 1023ull);
        int r2 = (int)((rec2 >> sh) & 1023ull);
        uint4 g1 = *reinterpret_cast<const uint4*>(gbase + (size_t)r1 * gstride);
        uint4 g2 = *reinterpret_cast<const uint4*>(gbase + (size_t)r2 * gstride);
        acc[0] += bflo(g1.x) + bflo(g2.x); acc[1] += bfhi(g1.x) + bfhi(g2.x);
        acc[2] += bflo(g1.y) + bflo(g2.y); acc[3] += bfhi(g1.y) + bfhi(g2.y);
        acc[4] += bflo(g1.z) + bflo(g2.z); acc[5] += bfhi(g1.z) + bfhi(g2.z);
        acc[6] += bflo(g1.w) + bflo(g2.w); acc[7] += bfhi(g1.w) + bfhi(g2.w);
      }
      if (e < deg) {
        u64 rec = lpx[beg + e];
        int r = (int)((rec >> sh) & 1023ull);
        uint4 gv = *reinterpret_cast<const uint4*>(gbase + (size_t)r * gstride);
        acc[0] += bflo(gv.x); acc[1] += bfhi(gv.x);
        acc[2] += bflo(gv.y); acc[3] += bfhi(gv.y);
        acc[4] += bflo(gv.z); acc[5] += bfhi(gv.z);
        acc[6] += bflo(gv.w); acc[7] += bfhi(gv.w);
      }
    }
    #pragma unroll
    for (int j = 0; j < 8; ++j) {
      float a1 = __shfl(acc[j], lane + 18);
      float a2 = __shfl(acc[j], lane + 36);
      acc[j] += a1 + a2;
    }
    float invc = (deg > 0) ? 1.f / (float)deg : 0.f;
    int dg = dst0 + d;
    ushort* ur = u + (size_t)br * UPLANE + (size_t)dg * KP;
    if (sub == 0) {
      u64 pvd = px[dg];
      int rowd = (int)((pvd >> sh) & 1023ull);
      uint4 sv = *reinterpret_cast<const uint4*>(gbase + (size_t)rowd * gstride);
      float s[8];
      s[0] = bflo(sv.x); s[1] = bfhi(sv.x);
      s[2] = bflo(sv.y); s[3] = bfhi(sv.y);
      s[4] = bflo(sv.z); s[5] = bfhi(sv.z);
      s[6] = bflo(sv.w); s[7] = bfhi(sv.w);
      bf16x8 o;
      #pragma unroll
      for (int j = 0; j < 8; ++j) o[j] = (short)f2bf(s[j] + acc[j] * invc);
      *reinterpret_cast<bf16x8*>(ur + g * 8) = o;
    } else if (lane == 18) {
      bf16x8 o = (bf16x8){0, 0, 0, 0, 0, 0, 0, 0};
      o[0] = (short)f2bf(deg > 0 ? 2.f : 1.f);
      *reinterpret_cast<bf16x8*>(ur + 144) = o;
    } else if (lane == 19) {
      *reinterpret_cast<bf16x8*>(ur + 152) = (bf16x8){0, 0, 0, 0, 0, 0, 0, 0};
    }
  }
}

// ---------------- layer-0 MFMA GEMM (unchanged) ----------------
__global__ __launch_bounds__(256)
void gemm_mfma2(const ushort* __restrict__ U, const ushort* __restrict__ Wt,
                ushort* __restrict__ h1) {
  __shared__ ushort Wth[128][KP + 8];
  int bid = blockIdx.x, tid = threadIdx.x;
  int rowblk = bid % GEMM_RB;
  int half = (bid / GEMM_RB) & 1;
  int br = bid / (2 * GEMM_RB);
  const ushort* Wsrc = Wt + ((size_t)br * HID + half * 128) * KP;
  for (int i = tid; i < 128 * (KP / 8); i += 256) {
    int r = i / (KP / 8), g = i - r * (KP / 8);
    *reinterpret_cast<bf16x8*>(&Wth[r][g * 8]) =
        *reinterpret_cast<const bf16x8*>(Wsrc + (size_t)r * KP + g * 8);
  }
  __syncthreads();
  int w = tid >> 6, lane = tid & 63, l15 = lane & 15, lhi = lane >> 4;
  int rowbase = rowblk * 256 + w * 64;
  const ushort* Ubr = U + (size_t)br * UPLANE;
  f32x4 acc[4][8];
  #pragma unroll
  for (int rt = 0; rt < 4; ++rt)
    #pragma unroll
    for (int ct = 0; ct < 8; ++ct) acc[rt][ct] = (f32x4){0.f, 0.f, 0.f, 0.f};
  #pragma unroll
  for (int ks = 0; ks < 5; ++ks) {
    bf16x8 bfr[8];
    #pragma unroll
    for (int ct = 0; ct < 8; ++ct)
      bfr[ct] = *reinterpret_cast<const bf16x8*>(&Wth[ct * 16 + l15][lhi * 8 + ks * 32]);
    #pragma unroll
    for (int rt = 0; rt < 4; ++rt) {
      int ar = rowbase + rt * 16 + l15;
      if (ar > 50047) ar = 50047;
      bf16x8 af = *reinterpret_cast<const bf16x8*>(Ubr + (size_t)ar * KP + lhi * 8 + ks * 32);
      #pragma unroll
      for (int ct = 0; ct < 8; ++ct)
        acc[rt][ct] = __builtin_amdgcn_mfma_f32_16x16x32_bf16(af, bfr[ct], acc[rt][ct], 0, 0, 0);
    }
  }
  ushort* h1p = h1 + (size_t)br * cN1 * HID + half * 128;
  #pragma unroll
  for (int rt = 0; rt < 4; ++rt) {
    #pragma unroll
    for (int r = 0; r < 4; ++r) {
      int row = rowbase + rt * 16 + lhi * 4 + r;
      if (row >= cN1) continue;
      #pragma unroll
      for (int ct = 0; ct < 8; ++ct)
        h1p[(size_t)row * HID + ct * 16 + l15] = f2bf(fmaxf(acc[rt][ct][r], 0.f));
    }
  }
}

// ---------------- fused layer-1: half-bucket blocks (unchanged) ------------
__global__ __launch_bounds__(256)
void agg1_fused(const ushort* __restrict__ h1, const int* __restrict__ bfill,
                const u64* __restrict__ packed, ushort* __restrict__ V) {
  __shared__ int lsrc[CAPH1];
  __shared__ int lcnt[32], lstart[32], lfill[32];
  int tid = threadIdx.x, w = tid >> 6, lane = tid & 63;
  int gbFull = blockIdx.x >> 1;
  int h = blockIdx.x & 1;
  int br = gbFull / NBA1;
  int bk = gbFull - br * NBA1;
  int fb = 2 * NBA0 + gbFull;
  int dst0 = bk * WN + h * 32;
  int nd = min(32, cN2 - dst0);
  if (nd <= 0) return;
  const ushort* h1p = h1 + (size_t)br * cN1 * HID;

  if (tid < 32) { lcnt[tid] = 0; lfill[tid] = 0; }
  __syncthreads();
  int ec = min(bfill[fb], CAP);
  const u64* pb = packed + L1PBASE + (size_t)gbFull * CAP;
  for (int i = tid; i < ec; i += 256) {
    unsigned ldst = (unsigned)(pb[i] >> 50) & 63u;
    if ((int)(ldst >> 5) == h) atomicAdd(&lcnt[ldst & 31u], 1);
  }
  __syncthreads();
  if (tid < 32) {
    int c = lcnt[tid]; int s = c;
    #pragma unroll
    for (int off = 1; off < 32; off <<= 1) {
      int t = __shfl_up(s, off);
      if (tid >= off) s += t;
    }
    lstart[tid] = s - c;
  }
  __syncthreads();
  for (int i = tid; i < ec; i += 256) {
    u64 v = pb[i];
    unsigned ldst = (unsigned)(v >> 50) & 63u;
    if ((int)(ldst >> 5) == h) {
      int l = (int)(ldst & 31u);
      int p = atomicAdd(&lfill[l], 1);
      int idx = lstart[l] + p;
      if (idx < CAPH1) lsrc[idx] = (int)(v & 0x3FFFFull);
    }
  }
  __syncthreads();

  for (int d = w; d < nd; d += 4) {
    int deg = lcnt[d], beg = lstart[d];
    float4 acc = make_float4(0.f, 0.f, 0.f, 0.f);
    int e = 0;
    for (; e + 4 <= deg; e += 4) {
      int sA = lsrc[beg + e], sB = lsrc[beg + e + 1];
      int sC = lsrc[beg + e + 2], sD = lsrc[beg + e + 3];
      ushort4 hA = *reinterpret_cast<const ushort4*>(h1p + (size_t)sA * HID + lane * 4);
      ushort4 hB = *reinterpret_cast<const ushort4*>(h1p + (size_t)sB * HID + lane * 4);
      ushort4 hC = *reinterpret_cast<const ushort4*>(h1p + (size_t)sC * HID + lane * 4);
      ushort4 hD = *reinterpret_cast<const ushort4*>(h1p + (size_t)sD * HID + lane * 4);
      acc.x += bf2f(hA.x) + bf2f(hB.x) + bf2f(hC.x) + bf2f(hD.x);
      acc.y += bf2f(hA.y) + bf2f(hB.y) + bf2f(hC.y) + bf2f(hD.y);
      acc.z += bf2f(hA.z) + bf2f(hB.z) + bf2f(hC.z) + bf2f(hD.z);
      acc.w += bf2f(hA.w) + bf2f(hB.w) + bf2f(hC.w) + bf2f(hD.w);
    }
    for (; e < deg; ++e) {
      int s = lsrc[beg + e];
      ushort4 hv = *reinterpret_cast<const ushort4*>(h1p + (size_t)s * HID + lane * 4);
      acc.x += bf2f(hv.x); acc.y += bf2f(hv.y); acc.z += bf2f(hv.z); acc.w += bf2f(hv.w);
    }
    float invc = (deg > 0) ? 1.f / (float)deg : 0.f;
    int dg = dst0 + d;
    ushort4 dv = *reinterpret_cast<const ushort4*>(h1p + (size_t)dg * HID + lane * 4);
    ushort4 o;
    o.x = f2bf(bf2f(dv.x) + acc.x * invc);
    o.y = f2bf(bf2f(dv.y) + acc.y * invc);
    o.z = f2bf(bf2f(dv.z) + acc.z * invc);
    o.w = f2bf(bf2f(dv.w) + acc.w * invc);
    *reinterpret_cast<ushort4*>(V + (size_t)dg * KT + br * HID + lane * 4) = o;
  }
}

// ---------------- tail MFMA GEMM: K-split across 2 waves (unchanged) -------
__global__ __launch_bounds__(128)
void tail_gemm(const ushort* __restrict__ V, const ushort* __restrict__ Gt,
               const float* __restrict__ gvec, float* __restrict__ out) {
  __shared__ f32x4 red[16][64];
  int tid = threadIdx.x;
  int wv = tid >> 6, lane = tid & 63;
  int l15 = lane & 15, lhi = lane >> 4;
  int rowW = blockIdx.x * 16;
  f32x4 acc[16];
  #pragma unroll
  for (int t = 0; t < 16; ++t) acc[t] = (f32x4){0.f, 0.f, 0.f, 0.f};
  const ushort* vp = V + (size_t)(rowW + l15) * KT + lhi * 8 + wv * 256;
  const ushort* gp = Gt + (size_t)l15 * KT + lhi * 8 + wv * 256;
  #pragma unroll
  for (int ks = 0; ks < 8; ++ks) {
    bf16x8 a = *reinterpret_cast<const bf16x8*>(vp + ks * 32);
    #pragma unroll
    for (int t = 0; t < 16; ++t) {
      bf16x8 b = *reinterpret_cast<const bf16x8*>(gp + (size_t)t * 16 * KT + ks * 32);
      acc[t] = __builtin_amdgcn_mfma_f32_16x16x32_bf16(a, b, acc[t], 0, 0, 0);
    }
  }
  if (wv == 1) {
    #pragma unroll
    for (int t = 0; t < 16; ++t) red[t][lane] = acc[t];
  }
  __syncthreads();
  if (wv == 0) {
    int r0 = rowW + lhi * 4;
    #pragma unroll
    for (int t = 0; t < 16; ++t) {
      f32x4 o = acc[t] + red[t][lane];
      int col = t * 16 + l15;
      float gv = gvec[col];
      float* dst = (col < 128) ? out + (size_t)r0 * OUTD + col
                               : out + (size_t)cN2 * OUTD + (size_t)r0 * OUTD + (col - 128);
      #pragma unroll
      for (int r = 0; r < 4; ++r)
        dst[(size_t)r * OUTD] = o[r] + gv;
    }
  }
}

// ---------------- launch ----------------
extern "C" void kernel_launch(void* const* d_in, const int* in_sizes, int n_in,
                              void* d_out, int out_size, void* d_ws, size_t ws_size,
                              hipStream_t stream) {
  const int* x = (const int*)d_in[0];
  struct Branch {
    const int *e0s, *e0d, *e1s, *e1d;
    const float *t0, *t1, *t2, *t3, *t4, *Win, *bin, *Wout, *bout;
  };
  auto mk = [&](int b) {
    Branch B;
    B.e0s = (const int*)d_in[b + 0];
    B.e0d = (const int*)d_in[b + 1];
    B.e1s = (const int*)d_in[b + 2];
    B.e1d = (const int*)d_in[b + 3];
    B.t0  = (const float*)d_in[b + 4];
    B.t1  = (const float*)d_in[b + 5];
    B.t2  = (const float*)d_in[b + 6];
    B.t3  = (const float*)d_in[b + 7];
    B.t4  = (const float*)d_in[b + 8];
    B.Win = (const float*)d_in[b + 9];
    B.bin = (const float*)d_in[b + 10];
    B.Wout= (const float*)d_in[b + 11];
    B.bout= (const float*)d_in[b + 12];
    return B;
  };
  Branch SB = mk(1), CB = mk(14);
  const float* Ws2c = (const float*)d_in[27];
  const float* Wc2s = (const float*)d_in[28];
  const float* a1p  = (const float*)d_in[29];
  const float* a2p  = (const float*)d_in[30];
  const float* b2p  = (const float*)d_in[31];

  // workspace layout (px/btab alias V region — V written only in agg1)
  char* ws = (char*)d_ws;
  ushort* u    = (ushort*)(ws + 0);            // 32,030,720
  ushort* h1   = (ushort*)(ws + 32030720);     // 51,200,000
  ushort* V    = (ushort*)(ws + 83230720);     // 10,240,000
  u64*   px    = (u64*)   (ws + 83230720);     // 1,600,000 (alias V)
  ushort* btab = (ushort*)(ws + 84830720);     // 576,000 (alias V)
  float*  M    = (float*) (ws + 93470720);     // 262,144
  ushort* Gt   = (ushort*)(ws + 93732864);     // 262,144
  float*  gvec = (float*) (ws + 93995008);     // 1,024
  ushort* Wt   = (ushort*)(ws + 93996032);     // 163,840
  int*   bfill = (int*)   (ws + 94159872);     // 1878*4 (pad to 7,680)
  u64*   packed= (u64*)   (ws + 94167552);     // 19,230,720 (end ~113.4MB)

  prep1<<<P1_TOT, 256, 0, stream>>>(x,
      SB.t0, SB.t1, SB.t2, SB.t3, SB.t4,
      CB.t0, CB.t1, CB.t2, CB.t3, CB.t4,
      SB.Win, CB.Win, SB.bin, CB.bin,
      Ws2c, Wc2s, a1p, a2p, b2p,
      px, bfill, btab, Wt, M);
  prep2<<<513, 256, 0, stream>>>(SB.Wout, CB.Wout, SB.bout, CB.bout, M, Gt, gvec);

  bucketize_v8<<<2 * NCH0 + 2 * NCH1, 512, 0, stream>>>(
      SB.e0s, SB.e0d, CB.e0s, CB.e0d, SB.e1s, SB.e1d, CB.e1s, CB.e1d,
      px, bfill, packed);

  agg0_fused<<<2 * NBA0, 256, 0, stream>>>(px, btab, bfill, packed, u);
  gemm_mfma2<<<4 * GEMM_RB, 256, 0, stream>>>(u, Wt, h1);
  agg1_fused<<<4 * NBA1, 256, 0, stream>>>(h1, bfill, packed, V);
  tail_gemm<<<TAIL_NB, 128, 0, stream>>>(V, Gt, gvec, (float*)d_out);
}

// Round 20
// 214.000 us; speedup vs baseline: 1.4410x; 1.0105x over previous
//
#include <hip/hip_runtime.h>

// ---------------- problem constants ----------------
constexpr int cN0 = 200000, cN1 = 50000, cN2 = 10000;
constexpr int cE0 = 800000, cE1 = 160000;
constexpr int GD  = 144;
constexpr int KP  = 160;       // padded K for MFMA (col 144 = bias-multiplier lane)
constexpr int HID = 256, OUTD = 128;
constexpr int KT  = 512;

constexpr int WN   = 64, CAP = 1280;
constexpr int NBA0 = (cN1 + WN - 1) / WN;     // 782
constexpr int NBA1 = (cN2 + WN - 1) / WN;     // 157
constexpr int NFILL = 2 * NBA0 + 2 * NBA1;    // 1878
constexpr size_t L1PBASE = (size_t)(2 * NBA0) * CAP;

constexpr int GEMM_RB = (50048 + 255) / 256;  // 196
constexpr int TAIL_NB = cN2 / 16;             // 625
constexpr size_t UPLANE = (size_t)50048 * KP;
constexpr int BT_STRIDE = 144000;
constexpr int CAPH1 = 768;

constexpr int CHUNK = 4096;
constexpr int NCH0  = (cE0 + CHUNK - 1) / CHUNK; // 196
constexpr int NCH1  = (cE1 + CHUNK - 1) / CHUNK; // 40

// prep1 grid regions
constexpr int P1_PACK = (cN0 + 255) / 256;         // 782
constexpr int P1_BTAB = (288000 + 255) / 256;      // 1125
constexpr int P1_WT   = (81920 + 255) / 256;       // 320
constexpr int P1_SMALL = 128;
constexpr int P1_TOT  = P1_PACK + P1_BTAB + P1_WT + P1_SMALL;

typedef __attribute__((ext_vector_type(8))) short bf16x8;
typedef __attribute__((ext_vector_type(4))) float f32x4;
typedef unsigned long long u64;
constexpr u64 PXMASK = (1ull << 50) - 1;

__device__ __forceinline__ ushort f2bf(float f) {
  union { float f; unsigned u; } v; v.f = f;
  unsigned r = (v.u + 0x7FFFu + ((v.u >> 16) & 1u)) >> 16;
  return (ushort)r;
}
__device__ __forceinline__ float bf2f(ushort u) {
  union { unsigned u; float f; } v; v.u = ((unsigned)u) << 16;
  return v.f;
}
__device__ __forceinline__ float bflo(unsigned v) {
  union { unsigned u; float f; } x; x.u = v << 16; return x.f;
}
__device__ __forceinline__ float bfhi(unsigned v) {
  union { unsigned u; float f; } x; x.u = v & 0xFFFF0000u; return x.f;
}

// ---------------- prep1: pack_x + bfill-zero + btab + Wt + M ---------------
__global__ __launch_bounds__(256)
void prep1(const int* __restrict__ x,
           const float* __restrict__ s_t0, const float* __restrict__ s_t1,
           const float* __restrict__ s_t2, const float* __restrict__ s_t3,
           const float* __restrict__ s_t4,
           const float* __restrict__ c_t0, const float* __restrict__ c_t1,
           const float* __restrict__ c_t2, const float* __restrict__ c_t3,
           const float* __restrict__ c_t4,
           const float* __restrict__ Ws, const float* __restrict__ Wc,
           const float* __restrict__ bs, const float* __restrict__ bc,
           const float* __restrict__ Ws2c, const float* __restrict__ Wc2s,
           const float* __restrict__ a1p, const float* __restrict__ a2p,
           const float* __restrict__ b2p,
           u64* __restrict__ px, int* __restrict__ bfill,
           ushort* __restrict__ btab, ushort* __restrict__ Wt,
           float* __restrict__ M) {
  int bid = blockIdx.x, tid = threadIdx.x;
  if (bid < P1_PACK) {
    int i = bid * 256 + tid;
    if (i < NFILL) bfill[i] = 0;
    if (i < cN0) {
      const int* xp = x + (size_t)i * 5;
      u64 v = (u64)(xp[0] & 1023)
            | ((u64)(xp[1] & 1023) << 10)
            | ((u64)(xp[2] & 1023) << 20)
            | ((u64)(xp[3] & 1023) << 30)
            | ((u64)(xp[4] & 1023) << 40);
      px[i] = v;
    }
  } else if (bid < P1_PACK + P1_BTAB) {
    int idx = (bid - P1_PACK) * 256 + tid;
    if (idx < 288000) {
      int br = idx / 144000;
      int rem = idx - br * 144000;
      int row = rem / 144, j = rem - row * 144;
      const float* t; int col, off, dim;
      if (j < 32)      { t = br ? c_t0 : s_t0; col = j;      off = 0;     dim = 32; }
      else if (j < 48) { t = br ? c_t1 : s_t1; col = j - 32; off = 32000; dim = 16; }
      else if (j < 64) { t = br ? c_t2 : s_t2; col = j - 48; off = 48000; dim = 16; }
      else if (j < 80) { t = br ? c_t3 : s_t3; col = j - 64; off = 64000; dim = 16; }
      else             { t = br ? c_t4 : s_t4; col = j - 80; off = 80000; dim = 64; }
      btab[(size_t)br * BT_STRIDE + off + row * dim + col] =
          f2bf(t[(size_t)row * dim + col]);
    }
  } else if (bid < P1_PACK + P1_BTAB + P1_WT) {
    int idx = (bid - P1_PACK - P1_BTAB) * 256 + tid;
    if (idx < 81920) {
      int br = idx / 40960;
      int rem = idx - br * 40960;
      int n = rem / 160, k = rem - n * 160;
      const float* W = br ? Wc : Ws;
      const float* b = br ? bc : bs;
      float v = (k < GD) ? W[(size_t)k * HID + n] : ((k == GD) ? b[n] : 0.f);
      Wt[(size_t)br * HID * KP + n * KP + k] = f2bf(v);
    }
  } else {
    int r = bid - P1_PACK - P1_BTAB - P1_WT;   // 0..127
    if (tid < 128) {
      int c = tid;
      float A1 = a1p[0], A2 = a2p[0], B2 = b2p[0];
      float c0 = 1.f - A2 - B2;
      float c1 = A2 + B2 * (1.f - A1);
      float c2 = A1 * B2;
      float s1 = 0.f, s4 = 0.f;
      for (int k = 0; k < 128; ++k) {
        s1 += Ws2c[r * 128 + k] * Wc2s[k * 128 + c];
        s4 += Wc2s[r * 128 + k] * Ws2c[k * 128 + c];
      }
      float eye = (r == c) ? c0 : 0.f;
      M[0 * 16384 + r * 128 + c] = c2 * s1 + eye;
      M[1 * 16384 + r * 128 + c] = c1 * Wc2s[r * 128 + c];
      M[2 * 16384 + r * 128 + c] = c1 * Ws2c[r * 128 + c];
      M[3 * 16384 + r * 128 + c] = c2 * s4 + eye;
    }
  }
}

// ---------------- prep2: build_G + build_gvec (depends on M) ---------------
__global__ __launch_bounds__(256)
void prep2(const float* __restrict__ Wout_s, const float* __restrict__ Wout_c,
           const float* __restrict__ b_s, const float* __restrict__ b_c,
           const float* __restrict__ M,
           ushort* __restrict__ Gt, float* __restrict__ gvec) {
  __shared__ float wr[128];
  int k = blockIdx.x, j = threadIdx.x;
  if (k < 512) {
    const float* wrow = (k < 256) ? &Wout_s[(size_t)k * 128] : &Wout_c[(size_t)(k - 256) * 128];
    if (j < 128) wr[j] = wrow[j];
    __syncthreads();
    const float* Mm = (j < 128) ? (k < 256 ? M : M + 16384)
                                : (k < 256 ? M + 2 * 16384 : M + 3 * 16384);
    int jj = j & 127;
    float s = 0.f;
    for (int t = 0; t < 128; ++t) s += wr[t] * Mm[t * 128 + jj];
    Gt[(size_t)j * KT + k] = f2bf(s);
  } else {
    int jj = j & 127;
    const float* Ma = (j < 128) ? M : M + 2 * 16384;
    const float* Mb = (j < 128) ? M + 16384 : M + 3 * 16384;
    float s = 0.f;
    for (int t = 0; t < 128; ++t)
      s += b_s[t] * Ma[t * 128 + jj] + b_c[t] * Mb[t * 128 + jj];
    gvec[j] = s;
  }
}

// ---------------- bucketize v8 (unchanged from R18) ----------------
__global__ __launch_bounds__(512)
void bucketize_v8(const int* __restrict__ s0, const int* __restrict__ d0,
                  const int* __restrict__ s1, const int* __restrict__ d1,
                  const int* __restrict__ s2, const int* __restrict__ d2,
                  const int* __restrict__ s3, const int* __restrict__ d3,
                  const u64* __restrict__ px,
                  int* __restrict__ bfill, u64* __restrict__ packed) {
  __shared__ ushort rawD[CHUNK];
  __shared__ u64 sed[CHUNK];
  __shared__ int lcnt[NBA0], lstart[NBA0], gbase_s[NBA0], lfill[NBA0];
  int bid = blockIdx.x, tid = threadIdx.x;
  const int *sp, *dp; int E, blk, NB, fbase, isL0;
  u64* pb;
  if (bid < NCH0) {
    sp = s0; dp = d0; E = cE0; blk = bid;             NB = NBA0;
    fbase = 0;               pb = packed; isL0 = 1;
  } else if (bid < 2 * NCH0) {
    sp = s1; dp = d1; E = cE0; blk = bid - NCH0;      NB = NBA0;
    fbase = NBA0;            pb = packed + (size_t)NBA0 * CAP; isL0 = 1;
  } else if (bid < 2 * NCH0 + NCH1) {
    sp = s2; dp = d2; E = cE1; blk = bid - 2 * NCH0;  NB = NBA1;
    fbase = 2 * NBA0;        pb = packed + L1PBASE; isL0 = 0;
  } else {
    sp = s3; dp = d3; E = cE1; blk = bid - 2 * NCH0 - NCH1; NB = NBA1;
    fbase = 2 * NBA0 + NBA1; pb = packed + L1PBASE + (size_t)NBA1 * CAP; isL0 = 0;
  }
  int base = blk * CHUNK;
  int n = min(CHUNK, E - base);
  bool full = (n == CHUNK);

  for (int i = tid; i < NB; i += 512) { lcnt[i] = 0; lfill[i] = 0; }
  __syncthreads();
  {
    int dds[8];
    if (full) {
      int4 a = *reinterpret_cast<const int4*>(dp + base + tid * 4);
      int4 b = *reinterpret_cast<const int4*>(dp + base + 2048 + tid * 4);
      dds[0] = a.x; dds[1] = a.y; dds[2] = a.z; dds[3] = a.w;
      dds[4] = b.x; dds[5] = b.y; dds[6] = b.z; dds[7] = b.w;
    } else {
      #pragma unroll
      for (int k = 0; k < 8; ++k) {
        int i = (k < 4) ? tid * 4 + k : 2048 + tid * 4 + (k - 4);
        dds[k] = (i < n) ? dp[base + i] : -1;
      }
    }
    #pragma unroll
    for (int k = 0; k < 8; ++k) {
      int i = (k < 4) ? tid * 4 + k : 2048 + tid * 4 + (k - 4);
      if (i < n) {
        rawD[i] = (ushort)dds[k];
        atomicAdd(&lcnt[dds[k] >> 6], 1);
      }
    }
  }
  __syncthreads();
  if (tid < 64) {
    int lane = tid;
    int i0 = lane * 13;
    int v[13], s = 0;
    #pragma unroll
    for (int j = 0; j < 13; ++j) {
      v[j] = (i0 + j < NB) ? lcnt[i0 + j] : 0;
      s += v[j];
    }
    int tot = s;
    #pragma unroll
    for (int off = 1; off < 64; off <<= 1) {
      int t = __shfl_up(s, off);
      if (lane >= off) s += t;
    }
    int excl = s - tot;
    #pragma unroll
    for (int j = 0; j < 13; ++j) {
      if (i0 + j < NB) lstart[i0 + j] = excl;
      excl += v[j];
    }
  }
  __syncthreads();
  {
    int srcs[8];
    if (full) {
      int4 a = *reinterpret_cast<const int4*>(sp + base + tid * 4);
      int4 b = *reinterpret_cast<const int4*>(sp + base + 2048 + tid * 4);
      srcs[0] = a.x; srcs[1] = a.y; srcs[2] = a.z; srcs[3] = a.w;
      srcs[4] = b.x; srcs[5] = b.y; srcs[6] = b.z; srcs[7] = b.w;
    } else {
      #pragma unroll
      for (int k = 0; k < 8; ++k) {
        int i = (k < 4) ? tid * 4 + k : 2048 + tid * 4 + (k - 4);
        srcs[k] = (i < n) ? sp[base + i] : 0;
      }
    }
    u64 rec[8];
    if (isL0) {
      #pragma unroll
      for (int k = 0; k < 8; ++k) rec[k] = px[srcs[k]];
    } else {
      #pragma unroll
      for (int k = 0; k < 8; ++k) rec[k] = (u64)(unsigned)srcs[k];
    }
    #pragma unroll
    for (int k = 0; k < 8; ++k) {
      int i = (k < 4) ? tid * 4 + k : 2048 + tid * 4 + (k - 4);
      if (i < n) {
        int dd = rawD[i];
        int b = dd >> 6;
        int p = atomicAdd(&lfill[b], 1);
        sed[lstart[b] + p] = rec[k] | ((u64)(unsigned)(dd & 63) << 50);
      }
    }
  }
  __syncthreads();
  for (int b = tid; b < NB; b += 512) {
    int cnt = lcnt[b];
    gbase_s[b] = (cnt > 0) ? atomicAdd(&bfill[fbase + b], cnt) : 0;
  }
  __syncthreads();
  int lane = tid & 63, wv = tid >> 6;
  for (int b = wv; b < NB; b += 8) {
    int cnt = lcnt[b];
    if (cnt == 0) continue;
    int gb0 = gbase_s[b];
    int st = lstart[b];
    for (int i = lane; i < cnt; i += 64) {
      int gp = gb0 + i;
      if (gp < CAP) pb[(size_t)b * CAP + gp] = sed[st + i];
    }
  }
}

// ---------------- fused layer-0: LDS-stashed records, 2-edge unroll --------
__global__ __launch_bounds__(256)
void agg0_fused(const u64* __restrict__ px, const ushort* __restrict__ btab,
                const int* __restrict__ bfill, const u64* __restrict__ packed,
                ushort* __restrict__ u) {
  __shared__ u64 lraw[CAP];                 // raw records (pass A stash)
  __shared__ u64 lpx[CAP];                  // dst-sorted px records
  __shared__ int lcnt[64], lstart[64], lfill[64];
  int tid = threadIdx.x, w = tid >> 6, lane = tid & 63;
  int gb = blockIdx.x;
  int br = gb / NBA0;
  int bk = gb - br * NBA0;
  int dst0 = bk * WN;
  int nd = min(WN, cN1 - dst0);

  const ushort* bt = btab + (size_t)br * BT_STRIDE;
  int sub = lane / 18;
  int g   = lane - sub * 18;
  const ushort* gbase; int sh, gstride;
  if (g < 4)       { gbase = bt + g * 8;              sh = 0;  gstride = 32; }
  else if (g < 6)  { gbase = bt + 32000 + (g - 4) * 8; sh = 10; gstride = 16; }
  else if (g < 8)  { gbase = bt + 48000 + (g - 6) * 8; sh = 20; gstride = 16; }
  else if (g < 10) { gbase = bt + 64000 + (g - 8) * 8; sh = 30; gstride = 16; }
  else             { gbase = bt + 80000 + (g - 10) * 8; sh = 40; gstride = 64; }

  if (tid < 64) { lcnt[tid] = 0; lfill[tid] = 0; }
  __syncthreads();
  int ec = min(bfill[gb], CAP);
  const u64* pb = packed + (size_t)gb * CAP;
  // pass A: single global read — stash record + count per-dst
  for (int i = tid; i < ec; i += 256) {
    u64 v = pb[i];
    lraw[i] = v;
    atomicAdd(&lcnt[(int)(v >> 50) & 63], 1);
  }
  __syncthreads();
  if (tid < 64) {
    int c = lcnt[tid]; int s = c;
    #pragma unroll
    for (int off = 1; off < 64; off <<= 1) {
      int t = __shfl_up(s, off);
      if (lane >= off) s += t;
    }
    lstart[tid] = s - c;
  }
  __syncthreads();
  // pass B: LDS -> LDS scatter by dst
  for (int i = tid; i < ec; i += 256) {
    u64 v = lraw[i];
    int l = (int)(v >> 50) & 63;
    int p = atomicAdd(&lfill[l], 1);
    lpx[lstart[l] + p] = v & PXMASK;
  }
  __syncthreads();

  for (int d = w; d < nd; d += 4) {
    int deg = lcnt[d], beg = lstart[d];
    float acc[8];
    #pragma unroll
    for (int j = 0; j < 8; ++j) acc[j] = 0.f;
    if (sub < 3) {
      int e = sub;
      for (; e + 3 < deg; e += 6) {
        u64 rec1 = lpx[beg + e];
        u64 rec2 = lpx[beg + e + 3];
        int r1 = (int)((rec1 >> sh) & 1023ull);
        int r2 = (int)((rec2 >> sh) & 1023ull);
        uint4 g1 = *reinterpret_cast<const uint4*>(gbase + (size_t)r1 * gstride);
        uint4 g2 = *reinterpret_cast<const uint4*>(gbase + (size_t)r2 * gstride);
        acc[0] += bflo(g1.x) + bflo(g2.x); acc[1] += bfhi(g1.x) + bfhi(g2.x);
        acc[2] += bflo(g1.y) + bflo(g2.y); acc[3] += bfhi(g1.y) + bfhi(g2.y);
        acc[4] += bflo(g1.z) + bflo(g2.z); acc[5] += bfhi(g1.z) + bfhi(g2.z);
        acc[6] += bflo(g1.w) + bflo(g2.w); acc[7] += bfhi(g1.w) + bfhi(g2.w);
      }
      if (e < deg) {
        u64 rec = lpx[beg + e];
        int r = (int)((rec >> sh) & 1023ull);
        uint4 gv = *reinterpret_cast<const uint4*>(gbase + (size_t)r * gstride);
        acc[0] += bflo(gv.x); acc[1] += bfhi(gv.x);
        acc[2] += bflo(gv.y); acc[3] += bfhi(gv.y);
        acc[4] += bflo(gv.z); acc[5] += bfhi(gv.z);
        acc[6] += bflo(gv.w); acc[7] += bfhi(gv.w);
      }
    }
    #pragma unroll
    for (int j = 0; j < 8; ++j) {
      float a1 = __shfl(acc[j], lane + 18);
      float a2 = __shfl(acc[j], lane + 36);
      acc[j] += a1 + a2;
    }
    float invc = (deg > 0) ? 1.f / (float)deg : 0.f;
    int dg = dst0 + d;
    ushort* ur = u + (size_t)br * UPLANE + (size_t)dg * KP;
    if (sub == 0) {
      u64 pvd = px[dg];
      int rowd = (int)((pvd >> sh) & 1023ull);
      uint4 sv = *reinterpret_cast<const uint4*>(gbase + (size_t)rowd * gstride);
      float s[8];
      s[0] = bflo(sv.x); s[1] = bfhi(sv.x);
      s[2] = bflo(sv.y); s[3] = bfhi(sv.y);
      s[4] = bflo(sv.z); s[5] = bfhi(sv.z);
      s[6] = bflo(sv.w); s[7] = bfhi(sv.w);
      bf16x8 o;
      #pragma unroll
      for (int j = 0; j < 8; ++j) o[j] = (short)f2bf(s[j] + acc[j] * invc);
      *reinterpret_cast<bf16x8*>(ur + g * 8) = o;
    } else if (lane == 18) {
      bf16x8 o = (bf16x8){0, 0, 0, 0, 0, 0, 0, 0};
      o[0] = (short)f2bf(deg > 0 ? 2.f : 1.f);
      *reinterpret_cast<bf16x8*>(ur + 144) = o;
    } else if (lane == 19) {
      *reinterpret_cast<bf16x8*>(ur + 152) = (bf16x8){0, 0, 0, 0, 0, 0, 0, 0};
    }
  }
}

// ---------------- layer-0 MFMA GEMM (unchanged) ----------------
__global__ __launch_bounds__(256)
void gemm_mfma2(const ushort* __restrict__ U, const ushort* __restrict__ Wt,
                ushort* __restrict__ h1) {
  __shared__ ushort Wth[128][KP + 8];
  int bid = blockIdx.x, tid = threadIdx.x;
  int rowblk = bid % GEMM_RB;
  int half = (bid / GEMM_RB) & 1;
  int br = bid / (2 * GEMM_RB);
  const ushort* Wsrc = Wt + ((size_t)br * HID + half * 128) * KP;
  for (int i = tid; i < 128 * (KP / 8); i += 256) {
    int r = i / (KP / 8), g = i - r * (KP / 8);
    *reinterpret_cast<bf16x8*>(&Wth[r][g * 8]) =
        *reinterpret_cast<const bf16x8*>(Wsrc + (size_t)r * KP + g * 8);
  }
  __syncthreads();
  int w = tid >> 6, lane = tid & 63, l15 = lane & 15, lhi = lane >> 4;
  int rowbase = rowblk * 256 + w * 64;
  const ushort* Ubr = U + (size_t)br * UPLANE;
  f32x4 acc[4][8];
  #pragma unroll
  for (int rt = 0; rt < 4; ++rt)
    #pragma unroll
    for (int ct = 0; ct < 8; ++ct) acc[rt][ct] = (f32x4){0.f, 0.f, 0.f, 0.f};
  #pragma unroll
  for (int ks = 0; ks < 5; ++ks) {
    bf16x8 bfr[8];
    #pragma unroll
    for (int ct = 0; ct < 8; ++ct)
      bfr[ct] = *reinterpret_cast<const bf16x8*>(&Wth[ct * 16 + l15][lhi * 8 + ks * 32]);
    #pragma unroll
    for (int rt = 0; rt < 4; ++rt) {
      int ar = rowbase + rt * 16 + l15;
      if (ar > 50047) ar = 50047;
      bf16x8 af = *reinterpret_cast<const bf16x8*>(Ubr + (size_t)ar * KP + lhi * 8 + ks * 32);
      #pragma unroll
      for (int ct = 0; ct < 8; ++ct)
        acc[rt][ct] = __builtin_amdgcn_mfma_f32_16x16x32_bf16(af, bfr[ct], acc[rt][ct], 0, 0, 0);
    }
  }
  ushort* h1p = h1 + (size_t)br * cN1 * HID + half * 128;
  #pragma unroll
  for (int rt = 0; rt < 4; ++rt) {
    #pragma unroll
    for (int r = 0; r < 4; ++r) {
      int row = rowbase + rt * 16 + lhi * 4 + r;
      if (row >= cN1) continue;
      #pragma unroll
      for (int ct = 0; ct < 8; ++ct)
        h1p[(size_t)row * HID + ct * 16 + l15] = f2bf(fmaxf(acc[rt][ct][r], 0.f));
    }
  }
}

// ---------------- fused layer-1: half-bucket + LDS-stashed records ---------
__global__ __launch_bounds__(256)
void agg1_fused(const ushort* __restrict__ h1, const int* __restrict__ bfill,
                const u64* __restrict__ packed, ushort* __restrict__ V) {
  __shared__ u64 lraw[CAP];                 // raw records (pass A stash)
  __shared__ int lsrc[CAPH1];
  __shared__ int lcnt[32], lstart[32], lfill[32];
  int tid = threadIdx.x, w = tid >> 6, lane = tid & 63;
  int gbFull = blockIdx.x >> 1;
  int h = blockIdx.x & 1;
  int br = gbFull / NBA1;
  int bk = gbFull - br * NBA1;
  int fb = 2 * NBA0 + gbFull;
  int dst0 = bk * WN + h * 32;
  int nd = min(32, cN2 - dst0);
  if (nd <= 0) return;
  const ushort* h1p = h1 + (size_t)br * cN1 * HID;

  if (tid < 32) { lcnt[tid] = 0; lfill[tid] = 0; }
  __syncthreads();
  int ec = min(bfill[fb], CAP);
  const u64* pb = packed + L1PBASE + (size_t)gbFull * CAP;
  // pass A: single global read — stash + count (own half)
  for (int i = tid; i < ec; i += 256) {
    u64 v = pb[i];
    lraw[i] = v;
    unsigned ldst = (unsigned)(v >> 50) & 63u;
    if ((int)(ldst >> 5) == h) atomicAdd(&lcnt[ldst & 31u], 1);
  }
  __syncthreads();
  if (tid < 32) {
    int c = lcnt[tid]; int s = c;
    #pragma unroll
    for (int off = 1; off < 32; off <<= 1) {
      int t = __shfl_up(s, off);
      if (tid >= off) s += t;
    }
    lstart[tid] = s - c;
  }
  __syncthreads();
  // pass B: LDS -> LDS scatter (own half)
  for (int i = tid; i < ec; i += 256) {
    u64 v = lraw[i];
    unsigned ldst = (unsigned)(v >> 50) & 63u;
    if ((int)(ldst >> 5) == h) {
      int l = (int)(ldst & 31u);
      int p = atomicAdd(&lfill[l], 1);
      int idx = lstart[l] + p;
      if (idx < CAPH1) lsrc[idx] = (int)(v & 0x3FFFFull);
    }
  }
  __syncthreads();

  for (int d = w; d < nd; d += 4) {
    int deg = lcnt[d], beg = lstart[d];
    float4 acc = make_float4(0.f, 0.f, 0.f, 0.f);
    int e = 0;
    for (; e + 4 <= deg; e += 4) {
      int sA = lsrc[beg + e], sB = lsrc[beg + e + 1];
      int sC = lsrc[beg + e + 2], sD = lsrc[beg + e + 3];
      ushort4 hA = *reinterpret_cast<const ushort4*>(h1p + (size_t)sA * HID + lane * 4);
      ushort4 hB = *reinterpret_cast<const ushort4*>(h1p + (size_t)sB * HID + lane * 4);
      ushort4 hC = *reinterpret_cast<const ushort4*>(h1p + (size_t)sC * HID + lane * 4);
      ushort4 hD = *reinterpret_cast<const ushort4*>(h1p + (size_t)sD * HID + lane * 4);
      acc.x += bf2f(hA.x) + bf2f(hB.x) + bf2f(hC.x) + bf2f(hD.x);
      acc.y += bf2f(hA.y) + bf2f(hB.y) + bf2f(hC.y) + bf2f(hD.y);
      acc.z += bf2f(hA.z) + bf2f(hB.z) + bf2f(hC.z) + bf2f(hD.z);
      acc.w += bf2f(hA.w) + bf2f(hB.w) + bf2f(hC.w) + bf2f(hD.w);
    }
    for (; e < deg; ++e) {
      int s = lsrc[beg + e];
      ushort4 hv = *reinterpret_cast<const ushort4*>(h1p + (size_t)s * HID + lane * 4);
      acc.x += bf2f(hv.x); acc.y += bf2f(hv.y); acc.z += bf2f(hv.z); acc.w += bf2f(hv.w);
    }
    float invc = (deg > 0) ? 1.f / (float)deg : 0.f;
    int dg = dst0 + d;
    ushort4 dv = *reinterpret_cast<const ushort4*>(h1p + (size_t)dg * HID + lane * 4);
    ushort4 o;
    o.x = f2bf(bf2f(dv.x) + acc.x * invc);
    o.y = f2bf(bf2f(dv.y) + acc.y * invc);
    o.z = f2bf(bf2f(dv.z) + acc.z * invc);
    o.w = f2bf(bf2f(dv.w) + acc.w * invc);
    *reinterpret_cast<ushort4*>(V + (size_t)dg * KT + br * HID + lane * 4) = o;
  }
}

// ---------------- tail MFMA GEMM: K-split across 2 waves (unchanged) -------
__global__ __launch_bounds__(128)
void tail_gemm(const ushort* __restrict__ V, const ushort* __restrict__ Gt,
               const float* __restrict__ gvec, float* __restrict__ out) {
  __shared__ f32x4 red[16][64];
  int tid = threadIdx.x;
  int wv = tid >> 6, lane = tid & 63;
  int l15 = lane & 15, lhi = lane >> 4;
  int rowW = blockIdx.x * 16;
  f32x4 acc[16];
  #pragma unroll
  for (int t = 0; t < 16; ++t) acc[t] = (f32x4){0.f, 0.f, 0.f, 0.f};
  const ushort* vp = V + (size_t)(rowW + l15) * KT + lhi * 8 + wv * 256;
  const ushort* gp = Gt + (size_t)l15 * KT + lhi * 8 + wv * 256;
  #pragma unroll
  for (int ks = 0; ks < 8; ++ks) {
    bf16x8 a = *reinterpret_cast<const bf16x8*>(vp + ks * 32);
    #pragma unroll
    for (int t = 0; t < 16; ++t) {
      bf16x8 b = *reinterpret_cast<const bf16x8*>(gp + (size_t)t * 16 * KT + ks * 32);
      acc[t] = __builtin_amdgcn_mfma_f32_16x16x32_bf16(a, b, acc[t], 0, 0, 0);
    }
  }
  if (wv == 1) {
    #pragma unroll
    for (int t = 0; t < 16; ++t) red[t][lane] = acc[t];
  }
  __syncthreads();
  if (wv == 0) {
    int r0 = rowW + lhi * 4;
    #pragma unroll
    for (int t = 0; t < 16; ++t) {
      f32x4 o = acc[t] + red[t][lane];
      int col = t * 16 + l15;
      float gv = gvec[col];
      float* dst = (col < 128) ? out + (size_t)r0 * OUTD + col
                               : out + (size_t)cN2 * OUTD + (size_t)r0 * OUTD + (col - 128);
      #pragma unroll
      for (int r = 0; r < 4; ++r)
        dst[(size_t)r * OUTD] = o[r] + gv;
    }
  }
}

// ---------------- launch ----------------
extern "C" void kernel_launch(void* const* d_in, const int* in_sizes, int n_in,
                              void* d_out, int out_size, void* d_ws, size_t ws_size,
                              hipStream_t stream) {
  const int* x = (const int*)d_in[0];
  struct Branch {
    const int *e0s, *e0d, *e1s, *e1d;
    const float *t0, *t1, *t2, *t3, *t4, *Win, *bin, *Wout, *bout;
  };
  auto mk = [&](int b) {
    Branch B;
    B.e0s = (const int*)d_in[b + 0];
    B.e0d = (const int*)d_in[b + 1];
    B.e1s = (const int*)d_in[b + 2];
    B.e1d = (const int*)d_in[b + 3];
    B.t0  = (const float*)d_in[b + 4];
    B.t1  = (const float*)d_in[b + 5];
    B.t2  = (const float*)d_in[b + 6];
    B.t3  = (const float*)d_in[b + 7];
    B.t4  = (const float*)d_in[b + 8];
    B.Win = (const float*)d_in[b + 9];
    B.bin = (const float*)d_in[b + 10];
    B.Wout= (const float*)d_in[b + 11];
    B.bout= (const float*)d_in[b + 12];
    return B;
  };
  Branch SB = mk(1), CB = mk(14);
  const float* Ws2c = (const float*)d_in[27];
  const float* Wc2s = (const float*)d_in[28];
  const float* a1p  = (const float*)d_in[29];
  const float* a2p  = (const float*)d_in[30];
  const float* b2p  = (const float*)d_in[31];

  // workspace layout (px/btab alias V region — V written only in agg1)
  char* ws = (char*)d_ws;
  ushort* u    = (ushort*)(ws + 0);            // 32,030,720
  ushort* h1   = (ushort*)(ws + 32030720);     // 51,200,000
  ushort* V    = (ushort*)(ws + 83230720);     // 10,240,000
  u64*   px    = (u64*)   (ws + 83230720);     // 1,600,000 (alias V)
  ushort* btab = (ushort*)(ws + 84830720);     // 576,000 (alias V)
  float*  M    = (float*) (ws + 93470720);     // 262,144
  ushort* Gt   = (ushort*)(ws + 93732864);     // 262,144
  float*  gvec = (float*) (ws + 93995008);     // 1,024
  ushort* Wt   = (ushort*)(ws + 93996032);     // 163,840
  int*   bfill = (int*)   (ws + 94159872);     // 1878*4 (pad to 7,680)
  u64*   packed= (u64*)   (ws + 94167552);     // 19,230,720 (end ~113.4MB)

  prep1<<<P1_TOT, 256, 0, stream>>>(x,
      SB.t0, SB.t1, SB.t2, SB.t3, SB.t4,
      CB.t0, CB.t1, CB.t2, CB.t3, CB.t4,
      SB.Win, CB.Win, SB.bin, CB.bin,
      Ws2c, Wc2s, a1p, a2p, b2p,
      px, bfill, btab, Wt, M);
  prep2<<<513, 256, 0, stream>>>(SB.Wout, CB.Wout, SB.bout, CB.bout, M, Gt, gvec);

  bucketize_v8<<<2 * NCH0 + 2 * NCH1, 512, 0, stream>>>(
      SB.e0s, SB.e0d, CB.e0s, CB.e0d, SB.e1s, SB.e1d, CB.e1s, CB.e1d,
      px, bfill, packed);

  agg0_fused<<<2 * NBA0, 256, 0, stream>>>(px, btab, bfill, packed, u);
  gemm_mfma2<<<4 * GEMM_RB, 256, 0, stream>>>(u, Wt, h1);
  agg1_fused<<<4 * NBA1, 256, 0, stream>>>(h1, bfill, packed, V);
  tail_gemm<<<TAIL_NB, 128, 0, stream>>>(V, Gt, gvec, (float*)d_out);
}